// Round 5
// baseline (1250.629 us; speedup 1.0000x reference)
//
#include <hip/hip_runtime.h>
#include <hip/hip_bf16.h>

using bf16 = __hip_bfloat16;
typedef __attribute__((ext_vector_type(4))) float  f32x4;

#define CMAX 256       // max nodes per edge (col nnz ~86 +- 9)
#define RMAX 128       // max edges per node (row nnz ~21.5 +- 4.5)

// ---------------------------------------------------------------------------
// One-shot fp32 -> bf16 conversion of all weights/biases into one arena.
// ---------------------------------------------------------------------------
struct ConvDesc { const float* src[12]; int dstoff[12]; int cnt[12]; };

__global__ __launch_bounds__(256)
void conv_weights(ConvDesc d, bf16* __restrict__ dst)
{
    const int seg = blockIdx.x >> 6;     // 12 segments x 64 blocks
    const int blk = blockIdx.x & 63;
    const float* __restrict__ s = d.src[seg];
    bf16* __restrict__ o = dst + d.dstoff[seg];
    const int n = d.cnt[seg];
    for (int i = blk * 256 + threadIdx.x; i < n; i += 64 * 256)
        o[i] = __float2bfloat16(s[i]);
}

// ---------------------------------------------------------------------------
// Sparse neighbor lists from incidence H [8192, 2048] fp32 (exactly 0.0/1.0).
// ---------------------------------------------------------------------------
__global__ __launch_bounds__(256)
void build_lists(const float* __restrict__ H, int* __restrict__ col_cnt,
                 unsigned short* __restrict__ col_idx, int* __restrict__ row_cnt,
                 unsigned short* __restrict__ row_idx)
{
    const int n = blockIdx.x, t = threadIdx.x;
    __shared__ int rc;
    if (t == 0) rc = 0;
    __syncthreads();

    const float* Hp = H + (size_t)n * 2048 + t * 8;
    f32x4 h0 = *(const f32x4*)Hp;
    f32x4 h1 = *(const f32x4*)(Hp + 4);
    float hv[8];
#pragma unroll
    for (int j = 0; j < 4; j++) { hv[j] = h0[j]; hv[4 + j] = h1[j]; }

#pragma unroll
    for (int j = 0; j < 8; j++) {
        if (hv[j] != 0.f) {
            const int e = t * 8 + j;
            const int sr = atomicAdd(&rc, 1);
            if (sr < RMAX) row_idx[(size_t)n * RMAX + sr] = (unsigned short)e;
            const int sc = atomicAdd(&col_cnt[e], 1);
            if (sc < CMAX) col_idx[(size_t)e * CMAX + sc] = (unsigned short)n;
        }
    }
    __syncthreads();
    if (t == 0) row_cnt[n] = (rc < RMAX) ? rc : RMAX;
}

// ---------------------------------------------------------------------------
// Diagnostic-grade GEMM (no MFMA): C[M,N] = A[M,K] * W[N,K]^T + bias[N].
// Block = one row m of A (staged to LDS fp32); thread t computes column
// n = blockIdx.y*256 + t by a straight dot product. K == 256.
// ---------------------------------------------------------------------------
template<bool AF32>
__global__ __launch_bounds__(256)
void gemm_simple(const void* __restrict__ Av, const bf16* __restrict__ W,
                 const bf16* __restrict__ bias, bf16* __restrict__ outB, int N)
{
    __shared__ float a[256];
    const int m = blockIdx.x;
    const int t = threadIdx.x;
    const int n = blockIdx.y * 256 + t;

    if (AF32) a[t] = ((const float*)Av)[(size_t)m * 256 + t];
    else      a[t] = __bfloat162float(((const bf16*)Av)[(size_t)m * 256 + t]);
    __syncthreads();

    const bf16* wr = W + (size_t)n * 256;
    float acc = 0.f;
#pragma unroll
    for (int c = 0; c < 32; c++) {
        union { f32x4 v; unsigned short u[8]; } wu;
        wu.v = *(const f32x4*)(wr + c * 8);
#pragma unroll
        for (int j = 0; j < 8; j++)
            acc += __uint_as_float(((unsigned)wu.u[j]) << 16) * a[c * 8 + j];
    }
    outB[(size_t)m * N + n] = __float2bfloat16(acc + __bfloat162float(bias[n]));
}

// ---------------------------------------------------------------------------
// Sparse masked attention: block = query row, wave = head (4 heads, hd=64).
// Masked entries contribute exp(-1e9-max)=0 exactly in the fp32 reference, so
// softmax over the unmasked (neighbor) set is exact.
// ---------------------------------------------------------------------------
__global__ __launch_bounds__(256)
void sparse_attn(const bf16* __restrict__ Q, const bf16* __restrict__ Kb,
                 const bf16* __restrict__ Vb, int kvs,
                 const int* __restrict__ cnts, const unsigned short* __restrict__ idx,
                 int lmax, int idxmask, bf16* __restrict__ out)
{
    __shared__ float sc[4][CMAX];
    __shared__ float qs[4][64];
    const int qi   = blockIdx.x;
    const int h    = threadIdx.x >> 6;
    const int lane = threadIdx.x & 63;

    int n = cnts[qi];
    if (n > lmax) n = lmax;
    if (n <= 0) {               // defensive (rows/cols guaranteed non-empty)
        out[(size_t)qi * 256 + h * 64 + lane] = __float2bfloat16(0.f);
        return;
    }
    const unsigned short* __restrict__ nl = idx + (size_t)qi * lmax;

    qs[h][lane] = __bfloat162float(Q[(size_t)qi * 256 + h * 64 + lane]) * 0.125f;
    __syncthreads();
    float qv[64];
#pragma unroll
    for (int j = 0; j < 64; j++) qv[j] = qs[h][j];

    // pass 1: scores, lane-per-neighbor
    float mx = -1e30f;
    for (int base = 0; base < n; base += 64) {
        const int i = base + lane;
        float s = -1e30f;
        if (i < n) {
            const int nb = ((int)nl[i]) & idxmask;
            const bf16* kr = Kb + (size_t)nb * kvs + h * 64;
            float a = 0.f;
#pragma unroll
            for (int c = 0; c < 8; c++) {
                union { f32x4 v; unsigned short u[8]; } ku;
                ku.v = *(const f32x4*)(kr + c * 8);
#pragma unroll
                for (int j = 0; j < 8; j++)
                    a += __uint_as_float(((unsigned)ku.u[j]) << 16) * qv[c * 8 + j];
            }
            s = a;
            sc[h][i] = s;
        }
        mx = fmaxf(mx, s);
    }
#pragma unroll
    for (int o = 32; o > 0; o >>= 1) mx = fmaxf(mx, __shfl_xor(mx, o));

    // pass 1.5: probabilities + sum
    float sum = 0.f;
    for (int base = 0; base < n; base += 64) {
        const int i = base + lane;
        if (i < n) {
            const float p = __expf(sc[h][i] - mx);
            sc[h][i] = p;
            sum += p;
        }
    }
#pragma unroll
    for (int o = 32; o > 0; o >>= 1) sum += __shfl_xor(sum, o);
    const float inv = 1.f / sum;

    // pass 2: PV accumulate, lane-per-dim
    float oacc = 0.f;
    for (int i = 0; i < n; i++) {
        const int nb = ((int)nl[i]) & idxmask;
        oacc += sc[h][i] * __bfloat162float(Vb[(size_t)nb * kvs + h * 64 + lane]);
    }
    out[(size_t)qi * 256 + h * 64 + lane] = __float2bfloat16(oacc * inv);
}

// ---------------------------------------------------------------------------
// Fused residual + LayerNorm (D=256): y = LN(xp + mh) * g + b.
// Writes fp32 into d_out (reference output dtype) and optional bf16 copy
// (needed when the LN result feeds the next stage's GEMM).
// ---------------------------------------------------------------------------
__global__ __launch_bounds__(256)
void residual_ln(const bf16* __restrict__ xp, const bf16* __restrict__ mh,
                 const float* __restrict__ g, const float* __restrict__ b,
                 float* __restrict__ outF, bf16* __restrict__ outB)
{
    const int row = blockIdx.x, t = threadIdx.x;
    __shared__ float red1[4], red2[4];
    const float x = __bfloat162float(xp[(size_t)row * 256 + t])
                  + __bfloat162float(mh[(size_t)row * 256 + t]);

    float s = x;
#pragma unroll
    for (int o = 32; o > 0; o >>= 1) s += __shfl_xor(s, o);
    if ((t & 63) == 0) red1[t >> 6] = s;
    __syncthreads();
    const float mu = (red1[0] + red1[1] + red1[2] + red1[3]) * (1.f / 256.f);

    const float d = x - mu;
    float v = d * d;
#pragma unroll
    for (int o = 32; o > 0; o >>= 1) v += __shfl_xor(v, o);
    if ((t & 63) == 0) red2[t >> 6] = v;
    __syncthreads();
    const float var = (red2[0] + red2[1] + red2[2] + red2[3]) * (1.f / 256.f);

    const float y = d * rsqrtf(var + 1e-5f) * g[t] + b[t];
    outF[(size_t)row * 256 + t] = y;
    if (outB) outB[(size_t)row * 256 + t] = __float2bfloat16(y);
}

// ---------------------------------------------------------------------------
extern "C" void kernel_launch(void* const* d_in, const int* in_sizes, int n_in,
                              void* d_out, int out_size, void* d_ws, size_t ws_size,
                              hipStream_t stream)
{
    const int N = 8192, E = 2048;

    float* out0 = (float*)d_out;                   // x_0_u [N,256] fp32
    float* out1 = (float*)d_out + (size_t)N * 256; // x_1_u [E,256] fp32

    // ---- workspace (~22 MB total, overlaid across stages) ----
    char* wp = (char*)d_ws;
    auto carve = [&](size_t bytes) { void* p = wp; wp += (bytes + 15) & ~size_t(15); return p; };

    bf16*  wcat    = (bf16*)          carve(657920 * 2);       // all weights+biases
    int*   col_cnt = (int*)           carve((size_t)E * 4);
    int*   row_cnt = (int*)           carve((size_t)N * 4);
    unsigned short* col_idx = (unsigned short*)carve((size_t)E * CMAX * 2);
    unsigned short* row_idx = (unsigned short*)carve((size_t)N * RMAX * 2);
    bf16*  x0p     = (bf16*)          carve((size_t)N * 256 * 2);   // residual + GEMM in
    bf16*  x1p     = (bf16*)          carve((size_t)E * 256 * 2);
    bf16*  x1u_b   = (bf16*)          carve((size_t)E * 256 * 2);   // bf16 copy of x_1_u
    bf16*  R1      = (bf16*)          carve((size_t)N * 512 * 2);   // 8 MB overlay
    bf16*  R2      = (bf16*)          carve((size_t)E * 256 * 3 * 2); // 3 MB overlay

    // overlay views
    bf16* kv1   = R1;                          // stage 1 [N,512]
    bf16* q2    = R1;                          // stage 2 [N,256]  (kv1 dead)
    bf16* attn2 = R1 + (size_t)N * 256;        // stage 2 [N,256]
    bf16* mha2  = R1;                          // stage 2 [N,256]  (q2 dead)
    bf16* q1    = R2;                          // stage 1 [E,256]
    bf16* attn1 = R2 + (size_t)E * 256;        // stage 1 [E,256]
    bf16* mha1  = R2 + (size_t)E * 512;        // stage 1 [E,256]
    bf16* kv2   = R2;                          // stage 2 [E,512]  (q1,attn1 dead)

    // wcat element offsets
    const int O_NW = 0, O_EW = 65536, O_AIW = 131072, O_AOW = 327680,
              O_BIW = 393216, O_BOW = 589824, O_NB = 655360, O_EB = 655616,
              O_AIB = 655872, O_AOB = 656640, O_BIB = 656896, O_BOB = 657664;

    ConvDesc cd;
    const int srcix[12] = {3, 5, 7, 9, 11, 13, 4, 6, 8, 10, 12, 14};
    const int offs [12] = {O_NW, O_EW, O_AIW, O_AOW, O_BIW, O_BOW,
                           O_NB, O_EB, O_AIB, O_AOB, O_BIB, O_BOB};
    const int cnts [12] = {65536, 65536, 196608, 65536, 196608, 65536,
                           256, 256, 768, 256, 768, 256};
    for (int i = 0; i < 12; i++) {
        cd.src[i] = (const float*)d_in[srcix[i]];
        cd.dstoff[i] = offs[i];
        cd.cnt[i] = cnts[i];
    }
    conv_weights<<<12 * 64, 256, 0, stream>>>(cd, wcat);

    hipMemsetAsync(col_cnt, 0, (size_t)E * 4, stream);
    build_lists<<<N, 256, 0, stream>>>((const float*)d_in[2], col_cnt, col_idx,
                                       row_cnt, row_idx);

    // projections (fp32 inputs -> bf16 out; x0p/x1p double as residuals)
    gemm_simple<true><<<dim3(N, 1), 256, 0, stream>>>(d_in[0], wcat + O_NW,
                                                      wcat + O_NB, x0p, 256);
    gemm_simple<true><<<dim3(E, 1), 256, 0, stream>>>(d_in[1], wcat + O_EW,
                                                      wcat + O_EB, x1p, 256);

    // ---- stage 1: node -> edge (edges query nodes; neighbors = H columns) ----
    gemm_simple<false><<<dim3(E, 1), 256, 0, stream>>>(x1p, wcat + O_AIW,
                                                       wcat + O_AIB, q1, 256);
    gemm_simple<false><<<dim3(N, 2), 256, 0, stream>>>(x0p, wcat + O_AIW + 65536,
                                                       wcat + O_AIB + 256, kv1, 512);
    sparse_attn<<<E, 256, 0, stream>>>(q1, kv1, kv1 + 256, 512,
                                       col_cnt, col_idx, CMAX, N - 1, attn1);
    gemm_simple<false><<<dim3(E, 1), 256, 0, stream>>>(attn1, wcat + O_AOW,
                                                       wcat + O_AOB, mha1, 256);
    residual_ln<<<E, 256, 0, stream>>>(x1p, mha1, (const float*)d_in[15],
                                       (const float*)d_in[16], out1, x1u_b);

    // ---- stage 2: edge -> node (nodes query updated edges; neighbors = H rows) ----
    gemm_simple<false><<<dim3(N, 1), 256, 0, stream>>>(x0p, wcat + O_BIW,
                                                       wcat + O_BIB, q2, 256);
    gemm_simple<false><<<dim3(E, 2), 256, 0, stream>>>(x1u_b, wcat + O_BIW + 65536,
                                                       wcat + O_BIB + 256, kv2, 512);
    sparse_attn<<<N, 256, 0, stream>>>(q2, kv2, kv2 + 256, 512,
                                       row_cnt, row_idx, RMAX, E - 1, attn2);
    gemm_simple<false><<<dim3(N, 1), 256, 0, stream>>>(attn2, wcat + O_BOW,
                                                       wcat + O_BOB, mha2, 256);
    residual_ln<<<N, 256, 0, stream>>>(x0p, mha2, (const float*)d_in[17],
                                       (const float*)d_in[18], out0, nullptr);
}

// Round 6
// 350.541 us; speedup vs baseline: 3.5677x; 3.5677x over previous
//
#include <hip/hip_runtime.h>
#include <hip/hip_bf16.h>

using bf16 = __hip_bfloat16;
typedef __attribute__((ext_vector_type(4))) float  f32x4;
typedef __attribute__((ext_vector_type(8))) short  s16x8;

#define QSTRIDE 1040   // bf16 elems per k-quad block: 128*8 data + 16 pad
#define CMAX 256       // max nodes per edge (col nnz ~86 +- 9)
#define RMAX 128       // max edges per node (row nnz ~21.5 +- 4.5)

// ---------------------------------------------------------------------------
// One-shot fp32 -> bf16 conversion of all weights/biases into one arena.
// ---------------------------------------------------------------------------
struct ConvDesc { const float* src[12]; int dstoff[12]; int cnt[12]; };

__global__ __launch_bounds__(256)
void conv_weights(ConvDesc d, bf16* __restrict__ dst)
{
    const int seg = blockIdx.x >> 6;     // 12 segments x 64 blocks
    const int blk = blockIdx.x & 63;
    const float* __restrict__ s = d.src[seg];
    bf16* __restrict__ o = dst + d.dstoff[seg];
    const int n = d.cnt[seg];
    for (int i = blk * 256 + threadIdx.x; i < n; i += 64 * 256)
        o[i] = __float2bfloat16(s[i]);
}

// ---------------------------------------------------------------------------
// Sparse neighbor lists from incidence H [8192, 2048] fp32 (exactly 0.0/1.0).
// ---------------------------------------------------------------------------
__global__ __launch_bounds__(256)
void build_lists(const float* __restrict__ H, int* __restrict__ col_cnt,
                 unsigned short* __restrict__ col_idx, int* __restrict__ row_cnt,
                 unsigned short* __restrict__ row_idx)
{
    const int n = blockIdx.x, t = threadIdx.x;
    __shared__ int rc;
    if (t == 0) rc = 0;
    __syncthreads();

    const float* Hp = H + (size_t)n * 2048 + t * 8;
    f32x4 h0 = *(const f32x4*)Hp;
    f32x4 h1 = *(const f32x4*)(Hp + 4);
    float hv[8];
#pragma unroll
    for (int j = 0; j < 4; j++) { hv[j] = h0[j]; hv[4 + j] = h1[j]; }

#pragma unroll
    for (int j = 0; j < 8; j++) {
        if (hv[j] != 0.f) {
            const int e = t * 8 + j;
            const int sr = atomicAdd(&rc, 1);
            if (sr < RMAX) row_idx[(size_t)n * RMAX + sr] = (unsigned short)e;
            const int sc = atomicAdd(&col_cnt[e], 1);
            if (sc < CMAX) col_idx[(size_t)e * CMAX + sc] = (unsigned short)n;
        }
    }
    __syncthreads();
    if (t == 0) row_cnt[n] = (rc < RMAX) ? rc : RMAX;
}

// ---------------------------------------------------------------------------
// MFMA GEMM: C[M,N] = A[M,K] * W[N,K]^T + bias[N], bf16 out.
// A fp32 (AF32, converted during staging) or bf16. Tile 128x128, BK=32,
// 16x16x32 MFMA. LDS layout [k-quad][row][8]. Verified mappings:
//   A-frag: m=lane&15, k=(lane>>4)*8+j ; B-frag: n=lane&15 same form
//   C/D:    col(n)=lane&15, row(m)=(lane>>4)*4+reg   [m89/m120]
// ---------------------------------------------------------------------------
template<bool AF32>
__global__ __launch_bounds__(256, 2)
void gemm_bt(const void* __restrict__ Av, const bf16* __restrict__ W,
             const bf16* __restrict__ bias, bf16* __restrict__ outB,
             int K, int N, int tilesN)
{
    __shared__ __align__(16) bf16 As[4 * QSTRIDE];
    __shared__ __align__(16) bf16 Bs[4 * QSTRIDE];

    const int t    = threadIdx.x;
    const int lane = t & 63;
    const int w    = t >> 6;
    const int wm   = (w >> 1) * 64;
    const int wn   = (w & 1) * 64;
    const int tm   = (blockIdx.x / tilesN) * 128;
    const int tn   = (blockIdx.x % tilesN) * 128;

    f32x4 acc[4][4];
#pragma unroll
    for (int i = 0; i < 4; i++)
#pragma unroll
        for (int j = 0; j < 4; j++)
#pragma unroll
            for (int r = 0; r < 4; r++) acc[i][j][r] = 0.f;

    // staging: tile = 128 rows x 4 k-quads = 512 chunks of 8 elems; 2/thread
    const int m0 = t >> 2,         q0 = t & 3;
    const int m1 = (t + 256) >> 2, q1 = (t + 256) & 3;

    const int fq = lane >> 4;    // k-quad
    const int fr = lane & 15;    // row-within-16

    for (int k0 = 0; k0 < K; k0 += 32) {
        s16x8 sa0, sa1;
        if (AF32) {
            const float* Af = (const float*)Av;
            f32x4 a0l = *(const f32x4*)(Af + (size_t)(tm + m0) * K + k0 + q0 * 8);
            f32x4 a0h = *(const f32x4*)(Af + (size_t)(tm + m0) * K + k0 + q0 * 8 + 4);
            f32x4 a1l = *(const f32x4*)(Af + (size_t)(tm + m1) * K + k0 + q1 * 8);
            f32x4 a1h = *(const f32x4*)(Af + (size_t)(tm + m1) * K + k0 + q1 * 8 + 4);
            union { s16x8 v; bf16 e[8]; } u0, u1;
#pragma unroll
            for (int j = 0; j < 4; j++) {
                u0.e[j] = __float2bfloat16(a0l[j]); u0.e[4 + j] = __float2bfloat16(a0h[j]);
                u1.e[j] = __float2bfloat16(a1l[j]); u1.e[4 + j] = __float2bfloat16(a1h[j]);
            }
            sa0 = u0.v; sa1 = u1.v;
        } else {
            const bf16* Ab = (const bf16*)Av;
            sa0 = *(const s16x8*)(Ab + (size_t)(tm + m0) * K + k0 + q0 * 8);
            sa1 = *(const s16x8*)(Ab + (size_t)(tm + m1) * K + k0 + q1 * 8);
        }
        s16x8 sb0 = *(const s16x8*)(W + (size_t)(tn + m0) * K + k0 + q0 * 8);
        s16x8 sb1 = *(const s16x8*)(W + (size_t)(tn + m1) * K + k0 + q1 * 8);

        __syncthreads();   // previous iteration's readers done
        *(s16x8*)&As[q0 * QSTRIDE + m0 * 8] = sa0;
        *(s16x8*)&As[q1 * QSTRIDE + m1 * 8] = sa1;
        *(s16x8*)&Bs[q0 * QSTRIDE + m0 * 8] = sb0;
        *(s16x8*)&Bs[q1 * QSTRIDE + m1 * 8] = sb1;
        __syncthreads();

        s16x8 af[4], bfv[4];
#pragma unroll
        for (int i = 0; i < 4; i++) {
            af[i]  = *(const s16x8*)&As[fq * QSTRIDE + (wm + i * 16 + fr) * 8];
            bfv[i] = *(const s16x8*)&Bs[fq * QSTRIDE + (wn + i * 16 + fr) * 8];
        }
#pragma unroll
        for (int i = 0; i < 4; i++)
#pragma unroll
            for (int j = 0; j < 4; j++)
                acc[i][j] = __builtin_amdgcn_mfma_f32_16x16x32_bf16(
                    af[i], bfv[j], acc[i][j], 0, 0, 0);
    }

#pragma unroll
    for (int j = 0; j < 4; j++) {
        const int ncol = tn + wn + j * 16 + fr;
        const float bj = __bfloat162float(bias[ncol]);
#pragma unroll
        for (int i = 0; i < 4; i++)
#pragma unroll
            for (int r = 0; r < 4; r++) {
                const int mrow = tm + wm + i * 16 + fq * 4 + r;
                outB[(size_t)mrow * N + ncol] = __float2bfloat16(acc[i][j][r] + bj);
            }
    }
}

// ---------------------------------------------------------------------------
// Sparse masked attention: block = query row, wave = head (4 heads, hd=64).
// Masked entries contribute exp(-1e9-max)=0 exactly in the fp32 reference, so
// softmax over the unmasked (neighbor) set is exact.
// ---------------------------------------------------------------------------
__global__ __launch_bounds__(256)
void sparse_attn(const bf16* __restrict__ Q, const bf16* __restrict__ Kb,
                 const bf16* __restrict__ Vb, int kvs,
                 const int* __restrict__ cnts, const unsigned short* __restrict__ idx,
                 int lmax, int idxmask, bf16* __restrict__ out)
{
    __shared__ float sc[4][CMAX];
    __shared__ float qs[4][64];
    const int qi   = blockIdx.x;
    const int h    = threadIdx.x >> 6;
    const int lane = threadIdx.x & 63;

    int n = cnts[qi];
    if (n > lmax) n = lmax;
    if (n <= 0) {
        out[(size_t)qi * 256 + h * 64 + lane] = __float2bfloat16(0.f);
        return;
    }
    const unsigned short* __restrict__ nl = idx + (size_t)qi * lmax;

    qs[h][lane] = __bfloat162float(Q[(size_t)qi * 256 + h * 64 + lane]) * 0.125f;
    __syncthreads();
    float qv[64];
#pragma unroll
    for (int j = 0; j < 64; j++) qv[j] = qs[h][j];

    // pass 1: scores, lane-per-neighbor
    float mx = -1e30f;
    for (int base = 0; base < n; base += 64) {
        const int i = base + lane;
        float s = -1e30f;
        if (i < n) {
            const int nb = ((int)nl[i]) & idxmask;
            const bf16* kr = Kb + (size_t)nb * kvs + h * 64;
            float a = 0.f;
#pragma unroll
            for (int c = 0; c < 8; c++) {
                union { f32x4 v; unsigned short u[8]; } ku;
                ku.v = *(const f32x4*)(kr + c * 8);
#pragma unroll
                for (int j = 0; j < 8; j++)
                    a += __uint_as_float(((unsigned)ku.u[j]) << 16) * qv[c * 8 + j];
            }
            s = a;
            sc[h][i] = s;
        }
        mx = fmaxf(mx, s);
    }
#pragma unroll
    for (int o = 32; o > 0; o >>= 1) mx = fmaxf(mx, __shfl_xor(mx, o));

    // pass 1.5: probabilities + sum
    float sum = 0.f;
    for (int base = 0; base < n; base += 64) {
        const int i = base + lane;
        if (i < n) {
            const float p = __expf(sc[h][i] - mx);
            sc[h][i] = p;
            sum += p;
        }
    }
#pragma unroll
    for (int o = 32; o > 0; o >>= 1) sum += __shfl_xor(sum, o);
    const float inv = 1.f / sum;

    // pass 2: PV accumulate, lane-per-dim
    float oacc = 0.f;
    for (int i = 0; i < n; i++) {
        const int nb = ((int)nl[i]) & idxmask;
        oacc += sc[h][i] * __bfloat162float(Vb[(size_t)nb * kvs + h * 64 + lane]);
    }
    out[(size_t)qi * 256 + h * 64 + lane] = __float2bfloat16(oacc * inv);
}

// ---------------------------------------------------------------------------
// Fused residual + LayerNorm (D=256): y = LN(xp + mh) * g + b.
// fp32 into d_out + optional bf16 copy for the next stage's GEMM input.
// ---------------------------------------------------------------------------
__global__ __launch_bounds__(256)
void residual_ln(const bf16* __restrict__ xp, const bf16* __restrict__ mh,
                 const float* __restrict__ g, const float* __restrict__ b,
                 float* __restrict__ outF, bf16* __restrict__ outB)
{
    const int row = blockIdx.x, t = threadIdx.x;
    __shared__ float red1[4], red2[4];
    const float x = __bfloat162float(xp[(size_t)row * 256 + t])
                  + __bfloat162float(mh[(size_t)row * 256 + t]);

    float s = x;
#pragma unroll
    for (int o = 32; o > 0; o >>= 1) s += __shfl_xor(s, o);
    if ((t & 63) == 0) red1[t >> 6] = s;
    __syncthreads();
    const float mu = (red1[0] + red1[1] + red1[2] + red1[3]) * (1.f / 256.f);

    const float d = x - mu;
    float v = d * d;
#pragma unroll
    for (int o = 32; o > 0; o >>= 1) v += __shfl_xor(v, o);
    if ((t & 63) == 0) red2[t >> 6] = v;
    __syncthreads();
    const float var = (red2[0] + red2[1] + red2[2] + red2[3]) * (1.f / 256.f);

    const float y = d * rsqrtf(var + 1e-5f) * g[t] + b[t];
    outF[(size_t)row * 256 + t] = y;
    if (outB) outB[(size_t)row * 256 + t] = __float2bfloat16(y);
}

// ---------------------------------------------------------------------------
extern "C" void kernel_launch(void* const* d_in, const int* in_sizes, int n_in,
                              void* d_out, int out_size, void* d_ws, size_t ws_size,
                              hipStream_t stream)
{
    const int N = 8192, E = 2048;

    float* out0 = (float*)d_out;                   // x_0_u [N,256] fp32
    float* out1 = (float*)d_out + (size_t)N * 256; // x_1_u [E,256] fp32

    // ---- workspace (~23 MB total, overlaid across stages) ----
    char* wp = (char*)d_ws;
    auto carve = [&](size_t bytes) { void* p = wp; wp += (bytes + 15) & ~size_t(15); return p; };

    bf16*  wcat    = (bf16*)          carve(657920 * 2);       // all weights+biases
    int*   col_cnt = (int*)           carve((size_t)E * 4);
    int*   row_cnt = (int*)           carve((size_t)N * 4);
    unsigned short* col_idx = (unsigned short*)carve((size_t)E * CMAX * 2);
    unsigned short* row_idx = (unsigned short*)carve((size_t)N * RMAX * 2);
    bf16*  x0p     = (bf16*)          carve((size_t)N * 256 * 2);   // residual + GEMM in
    bf16*  x1p     = (bf16*)          carve((size_t)E * 256 * 2);
    bf16*  x1u_b   = (bf16*)          carve((size_t)E * 256 * 2);   // bf16 copy of x_1_u
    bf16*  R1      = (bf16*)          carve((size_t)N * 512 * 2);   // 8 MB overlay
    bf16*  R2      = (bf16*)          carve((size_t)E * 256 * 3 * 2); // 3 MB overlay

    // overlay views
    bf16* kv1   = R1;                          // stage 1 [N,512]
    bf16* q2    = R1;                          // stage 2 [N,256]  (kv1 dead)
    bf16* attn2 = R1 + (size_t)N * 256;        // stage 2 [N,256]
    bf16* mha2  = R1;                          // stage 2 [N,256]  (q2 dead)
    bf16* q1    = R2;                          // stage 1 [E,256]
    bf16* attn1 = R2 + (size_t)E * 256;        // stage 1 [E,256]
    bf16* mha1  = R2 + (size_t)E * 512;        // stage 1 [E,256]
    bf16* kv2   = R2;                          // stage 2 [E,512]  (q1,attn1 dead)

    // wcat element offsets
    const int O_NW = 0, O_EW = 65536, O_AIW = 131072, O_AOW = 327680,
              O_BIW = 393216, O_BOW = 589824, O_NB = 655360, O_EB = 655616,
              O_AIB = 655872, O_AOB = 656640, O_BIB = 656896, O_BOB = 657664;

    ConvDesc cd;
    const int srcix[12] = {3, 5, 7, 9, 11, 13, 4, 6, 8, 10, 12, 14};
    const int offs [12] = {O_NW, O_EW, O_AIW, O_AOW, O_BIW, O_BOW,
                           O_NB, O_EB, O_AIB, O_AOB, O_BIB, O_BOB};
    const int cnts [12] = {65536, 65536, 196608, 65536, 196608, 65536,
                           256, 256, 768, 256, 768, 256};
    for (int i = 0; i < 12; i++) {
        cd.src[i] = (const float*)d_in[srcix[i]];
        cd.dstoff[i] = offs[i];
        cd.cnt[i] = cnts[i];
    }
    conv_weights<<<12 * 64, 256, 0, stream>>>(cd, wcat);

    hipMemsetAsync(col_cnt, 0, (size_t)E * 4, stream);
    build_lists<<<N, 256, 0, stream>>>((const float*)d_in[2], col_cnt, col_idx,
                                       row_cnt, row_idx);

    // projections (fp32 inputs -> bf16 out; x0p/x1p double as residuals)
    gemm_bt<true><<<(N/128)*2, 256, 0, stream>>>(d_in[0], wcat + O_NW,
                                                 wcat + O_NB, x0p, 256, 256, 2);
    gemm_bt<true><<<(E/128)*2, 256, 0, stream>>>(d_in[1], wcat + O_EW,
                                                 wcat + O_EB, x1p, 256, 256, 2);

    // ---- stage 1: node -> edge (edges query nodes; neighbors = H columns) ----
    gemm_bt<false><<<(E/128)*2, 256, 0, stream>>>(x1p, wcat + O_AIW,
                                                  wcat + O_AIB, q1, 256, 256, 2);
    gemm_bt<false><<<(N/128)*4, 256, 0, stream>>>(x0p, wcat + O_AIW + 65536,
                                                  wcat + O_AIB + 256, kv1, 256, 512, 4);
    sparse_attn<<<E, 256, 0, stream>>>(q1, kv1, kv1 + 256, 512,
                                       col_cnt, col_idx, CMAX, N - 1, attn1);
    gemm_bt<false><<<(E/128)*2, 256, 0, stream>>>(attn1, wcat + O_AOW,
                                                  wcat + O_AOB, mha1, 256, 256, 2);
    residual_ln<<<E, 256, 0, stream>>>(x1p, mha1, (const float*)d_in[15],
                                       (const float*)d_in[16], out1, x1u_b);

    // ---- stage 2: edge -> node (nodes query updated edges; neighbors = H rows) ----
    gemm_bt<false><<<(N/128)*2, 256, 0, stream>>>(x0p, wcat + O_BIW,
                                                  wcat + O_BIB, q2, 256, 256, 2);
    gemm_bt<false><<<(E/128)*4, 256, 0, stream>>>(x1u_b, wcat + O_BIW + 65536,
                                                  wcat + O_BIB + 256, kv2, 256, 512, 4);
    sparse_attn<<<N, 256, 0, stream>>>(q2, kv2, kv2 + 256, 512,
                                       row_cnt, row_idx, RMAX, E - 1, attn2);
    gemm_bt<false><<<(N/128)*2, 256, 0, stream>>>(attn2, wcat + O_BOW,
                                                  wcat + O_BOB, mha2, 256, 256, 2);
    residual_ln<<<N, 256, 0, stream>>>(x0p, mha2, (const float*)d_in[17],
                                       (const float*)d_in[18], out0, nullptr);
}

// Round 7
// 288.143 us; speedup vs baseline: 4.3403x; 1.2166x over previous
//
#include <hip/hip_runtime.h>
#include <hip/hip_bf16.h>

using bf16 = __hip_bfloat16;
typedef __attribute__((ext_vector_type(4))) float  f32x4;
typedef __attribute__((ext_vector_type(8))) short  s16x8;

#define QSTRIDE 1040   // bf16 elems per k-quad block: 128*8 data + 16 pad
#define CMAX 256       // max nodes per edge (col nnz ~86 +- 9)
#define RMAX 128       // max edges per node (row nnz ~21.5 +- 4.5)

// ---------------------------------------------------------------------------
// One-shot fp32 -> bf16 conversion of all weights/biases into one arena.
// ---------------------------------------------------------------------------
struct ConvDesc { const float* src[12]; int dstoff[12]; int cnt[12]; };

__global__ __launch_bounds__(256)
void conv_weights(ConvDesc d, bf16* __restrict__ dst)
{
    const int seg = blockIdx.x >> 6;     // 12 segments x 64 blocks
    const int blk = blockIdx.x & 63;
    const float* __restrict__ s = d.src[seg];
    bf16* __restrict__ o = dst + d.dstoff[seg];
    const int n = d.cnt[seg];
    for (int i = blk * 256 + threadIdx.x; i < n; i += 64 * 256)
        o[i] = __float2bfloat16(s[i]);
}

// ---------------------------------------------------------------------------
// Sparse neighbor lists from incidence H [8192, 2048] fp32 (exactly 0.0/1.0).
// ---------------------------------------------------------------------------
__global__ __launch_bounds__(256)
void build_lists(const float* __restrict__ H, int* __restrict__ col_cnt,
                 unsigned short* __restrict__ col_idx, int* __restrict__ row_cnt,
                 unsigned short* __restrict__ row_idx)
{
    const int n = blockIdx.x, t = threadIdx.x;
    __shared__ int rc;
    if (t == 0) rc = 0;
    __syncthreads();

    const float* Hp = H + (size_t)n * 2048 + t * 8;
    f32x4 h0 = *(const f32x4*)Hp;
    f32x4 h1 = *(const f32x4*)(Hp + 4);
    float hv[8];
#pragma unroll
    for (int j = 0; j < 4; j++) { hv[j] = h0[j]; hv[4 + j] = h1[j]; }

#pragma unroll
    for (int j = 0; j < 8; j++) {
        if (hv[j] != 0.f) {
            const int e = t * 8 + j;
            const int sr = atomicAdd(&rc, 1);
            if (sr < RMAX) row_idx[(size_t)n * RMAX + sr] = (unsigned short)e;
            const int sc = atomicAdd(&col_cnt[e], 1);
            if (sc < CMAX) col_idx[(size_t)e * CMAX + sc] = (unsigned short)n;
        }
    }
    __syncthreads();
    if (t == 0) row_cnt[n] = (rc < RMAX) ? rc : RMAX;
}

// ---------------------------------------------------------------------------
// MFMA GEMM: C[M,N] = A[M,K] * W[N,K]^T + bias[N], bf16 out.
// A fp32 (AF32, converted during staging) or bf16. Tile 128x128, BK=32,
// 16x16x32 MFMA. LDS layout [k-quad][row][8].
// ---------------------------------------------------------------------------
template<bool AF32>
__global__ __launch_bounds__(256, 2)
void gemm_bt(const void* __restrict__ Av, const bf16* __restrict__ W,
             const bf16* __restrict__ bias, bf16* __restrict__ outB,
             int K, int N, int tilesN)
{
    __shared__ __align__(16) bf16 As[4 * QSTRIDE];
    __shared__ __align__(16) bf16 Bs[4 * QSTRIDE];

    const int t    = threadIdx.x;
    const int lane = t & 63;
    const int w    = t >> 6;
    const int wm   = (w >> 1) * 64;
    const int wn   = (w & 1) * 64;
    const int tm   = (blockIdx.x / tilesN) * 128;
    const int tn   = (blockIdx.x % tilesN) * 128;

    f32x4 acc[4][4];
#pragma unroll
    for (int i = 0; i < 4; i++)
#pragma unroll
        for (int j = 0; j < 4; j++)
#pragma unroll
            for (int r = 0; r < 4; r++) acc[i][j][r] = 0.f;

    const int m0 = t >> 2,         q0 = t & 3;
    const int m1 = (t + 256) >> 2, q1 = (t + 256) & 3;

    const int fq = lane >> 4;
    const int fr = lane & 15;

    for (int k0 = 0; k0 < K; k0 += 32) {
        s16x8 sa0, sa1;
        if (AF32) {
            const float* Af = (const float*)Av;
            f32x4 a0l = *(const f32x4*)(Af + (size_t)(tm + m0) * K + k0 + q0 * 8);
            f32x4 a0h = *(const f32x4*)(Af + (size_t)(tm + m0) * K + k0 + q0 * 8 + 4);
            f32x4 a1l = *(const f32x4*)(Af + (size_t)(tm + m1) * K + k0 + q1 * 8);
            f32x4 a1h = *(const f32x4*)(Af + (size_t)(tm + m1) * K + k0 + q1 * 8 + 4);
            union { s16x8 v; bf16 e[8]; } u0, u1;
#pragma unroll
            for (int j = 0; j < 4; j++) {
                u0.e[j] = __float2bfloat16(a0l[j]); u0.e[4 + j] = __float2bfloat16(a0h[j]);
                u1.e[j] = __float2bfloat16(a1l[j]); u1.e[4 + j] = __float2bfloat16(a1h[j]);
            }
            sa0 = u0.v; sa1 = u1.v;
        } else {
            const bf16* Ab = (const bf16*)Av;
            sa0 = *(const s16x8*)(Ab + (size_t)(tm + m0) * K + k0 + q0 * 8);
            sa1 = *(const s16x8*)(Ab + (size_t)(tm + m1) * K + k0 + q1 * 8);
        }
        s16x8 sb0 = *(const s16x8*)(W + (size_t)(tn + m0) * K + k0 + q0 * 8);
        s16x8 sb1 = *(const s16x8*)(W + (size_t)(tn + m1) * K + k0 + q1 * 8);

        __syncthreads();
        *(s16x8*)&As[q0 * QSTRIDE + m0 * 8] = sa0;
        *(s16x8*)&As[q1 * QSTRIDE + m1 * 8] = sa1;
        *(s16x8*)&Bs[q0 * QSTRIDE + m0 * 8] = sb0;
        *(s16x8*)&Bs[q1 * QSTRIDE + m1 * 8] = sb1;
        __syncthreads();

        s16x8 af[4], bfv[4];
#pragma unroll
        for (int i = 0; i < 4; i++) {
            af[i]  = *(const s16x8*)&As[fq * QSTRIDE + (wm + i * 16 + fr) * 8];
            bfv[i] = *(const s16x8*)&Bs[fq * QSTRIDE + (wn + i * 16 + fr) * 8];
        }
#pragma unroll
        for (int i = 0; i < 4; i++)
#pragma unroll
            for (int j = 0; j < 4; j++)
                acc[i][j] = __builtin_amdgcn_mfma_f32_16x16x32_bf16(
                    af[i], bfv[j], acc[i][j], 0, 0, 0);
    }

#pragma unroll
    for (int j = 0; j < 4; j++) {
        const int ncol = tn + wn + j * 16 + fr;
        const float bj = __bfloat162float(bias[ncol]);
#pragma unroll
        for (int i = 0; i < 4; i++)
#pragma unroll
            for (int r = 0; r < 4; r++) {
                const int mrow = tm + wm + i * 16 + fq * 4 + r;
                outB[(size_t)mrow * N + ncol] = __float2bfloat16(acc[i][j][r] + bj);
            }
    }
}

// ---------------------------------------------------------------------------
// Sparse masked attention, vectorized gather. Block = query row, wave = head
// (4 heads, hd=64). Within a wave: 8 groups x 8 lanes; group = neighbor,
// lane = 8-dim slice (16 B loads; 8x128 B contiguous rows per iteration).
// Masked entries contribute exp(-1e9-max)=0 exactly in the reference.
// ---------------------------------------------------------------------------
__global__ __launch_bounds__(256)
void sparse_attn(const bf16* __restrict__ Q, const bf16* __restrict__ Kb,
                 const bf16* __restrict__ Vb, int kvs,
                 const int* __restrict__ cnts, const unsigned short* __restrict__ idx,
                 int lmax, int idxmask, bf16* __restrict__ out)
{
    __shared__ float sc[4][CMAX];
    __shared__ unsigned short nls[CMAX];
    const int qi   = blockIdx.x;
    const int h    = threadIdx.x >> 6;
    const int lane = threadIdx.x & 63;
    const int grp  = lane >> 3;   // neighbor slot within iteration
    const int sub  = lane & 7;    // 8-dim slice within head

    int n = cnts[qi];
    if (n > lmax) n = lmax;

    // stage neighbor list to LDS once (wave h==0)
    if (h == 0)
        for (int i = lane; i < n; i += 64)
            nls[i] = (unsigned short)(((int)idx[(size_t)qi * lmax + i]) & idxmask);
    __syncthreads();

    if (n <= 0) {
        out[(size_t)qi * 256 + h * 64 + lane] = __float2bfloat16(0.f);
        return;
    }

    // q slice: 8 dims per lane, pre-scaled
    float qv[8];
    {
        union { f32x4 v; unsigned short u[8]; } qu;
        qu.v = *(const f32x4*)(Q + (size_t)qi * 256 + h * 64 + sub * 8);
#pragma unroll
        for (int j = 0; j < 8; j++)
            qv[j] = __uint_as_float(((unsigned)qu.u[j]) << 16) * 0.125f;
    }

    // pass 1: scores (8 neighbors per iteration)
    float mx = -1e30f;
#pragma unroll 2
    for (int base = 0; base < n; base += 8) {
        const int i = base + grp;
        float s = -1e30f;
        if (i < n) {
            const int nb = nls[i];
            union { f32x4 v; unsigned short u[8]; } ku;
            ku.v = *(const f32x4*)(Kb + (size_t)nb * kvs + h * 64 + sub * 8);
            float a = 0.f;
#pragma unroll
            for (int j = 0; j < 8; j++)
                a += __uint_as_float(((unsigned)ku.u[j]) << 16) * qv[j];
            a += __shfl_xor(a, 1);   // sum within 8-lane group
            a += __shfl_xor(a, 2);
            a += __shfl_xor(a, 4);
            if (sub == 0) sc[h][i] = a;
            s = a;
        }
        mx = fmaxf(mx, s);
    }
#pragma unroll
    for (int o = 32; o > 0; o >>= 1) mx = fmaxf(mx, __shfl_xor(mx, o));

    // pass 1.5: probabilities + sum (lane-per-neighbor, LDS only)
    float sum = 0.f;
    for (int base = 0; base < n; base += 64) {
        const int i = base + lane;
        if (i < n) {
            const float p = __expf(sc[h][i] - mx);
            sc[h][i] = p;
            sum += p;
        }
    }
#pragma unroll
    for (int o = 32; o > 0; o >>= 1) sum += __shfl_xor(sum, o);
    const float inv = 1.f / sum;

    // pass 2: PV accumulate (8 neighbors per iteration, 16 B V loads)
    float oa[8];
#pragma unroll
    for (int j = 0; j < 8; j++) oa[j] = 0.f;
#pragma unroll 2
    for (int base = 0; base < n; base += 8) {
        const int i = base + grp;
        if (i < n) {
            const float p = sc[h][i];
            const int nb = nls[i];
            union { f32x4 v; unsigned short u[8]; } vu;
            vu.v = *(const f32x4*)(Vb + (size_t)nb * kvs + h * 64 + sub * 8);
#pragma unroll
            for (int j = 0; j < 8; j++)
                oa[j] += p * __uint_as_float(((unsigned)vu.u[j]) << 16);
        }
    }
    // reduce across the 8 groups (same sub -> same dim slice)
#pragma unroll
    for (int j = 0; j < 8; j++) {
        oa[j] += __shfl_xor(oa[j], 8);
        oa[j] += __shfl_xor(oa[j], 16);
        oa[j] += __shfl_xor(oa[j], 32);
    }
    if (grp == 0) {    // lanes 0..7 write 16 B each
        union { s16x8 v; bf16 e[8]; } ou;
#pragma unroll
        for (int j = 0; j < 8; j++) ou.e[j] = __float2bfloat16(oa[j] * inv);
        *(s16x8*)(out + (size_t)qi * 256 + h * 64 + sub * 8) = ou.v;
    }
}

// ---------------------------------------------------------------------------
// Fused residual + LayerNorm (D=256): y = LN(xp + mh) * g + b.
// fp32 into d_out + optional bf16 copy for the next stage's GEMM input.
// ---------------------------------------------------------------------------
__global__ __launch_bounds__(256)
void residual_ln(const bf16* __restrict__ xp, const bf16* __restrict__ mh,
                 const float* __restrict__ g, const float* __restrict__ b,
                 float* __restrict__ outF, bf16* __restrict__ outB)
{
    const int row = blockIdx.x, t = threadIdx.x;
    __shared__ float red1[4], red2[4];
    const float x = __bfloat162float(xp[(size_t)row * 256 + t])
                  + __bfloat162float(mh[(size_t)row * 256 + t]);

    float s = x;
#pragma unroll
    for (int o = 32; o > 0; o >>= 1) s += __shfl_xor(s, o);
    if ((t & 63) == 0) red1[t >> 6] = s;
    __syncthreads();
    const float mu = (red1[0] + red1[1] + red1[2] + red1[3]) * (1.f / 256.f);

    const float d = x - mu;
    float v = d * d;
#pragma unroll
    for (int o = 32; o > 0; o >>= 1) v += __shfl_xor(v, o);
    if ((t & 63) == 0) red2[t >> 6] = v;
    __syncthreads();
    const float var = (red2[0] + red2[1] + red2[2] + red2[3]) * (1.f / 256.f);

    const float y = d * rsqrtf(var + 1e-5f) * g[t] + b[t];
    outF[(size_t)row * 256 + t] = y;
    if (outB) outB[(size_t)row * 256 + t] = __float2bfloat16(y);
}

// ---------------------------------------------------------------------------
extern "C" void kernel_launch(void* const* d_in, const int* in_sizes, int n_in,
                              void* d_out, int out_size, void* d_ws, size_t ws_size,
                              hipStream_t stream)
{
    const int N = 8192, E = 2048;

    float* out0 = (float*)d_out;                   // x_0_u [N,256] fp32
    float* out1 = (float*)d_out + (size_t)N * 256; // x_1_u [E,256] fp32

    // ---- workspace (~23 MB total, overlaid across stages) ----
    char* wp = (char*)d_ws;
    auto carve = [&](size_t bytes) { void* p = wp; wp += (bytes + 15) & ~size_t(15); return p; };

    bf16*  wcat    = (bf16*)          carve(657920 * 2);       // all weights+biases
    int*   col_cnt = (int*)           carve((size_t)E * 4);
    int*   row_cnt = (int*)           carve((size_t)N * 4);
    unsigned short* col_idx = (unsigned short*)carve((size_t)E * CMAX * 2);
    unsigned short* row_idx = (unsigned short*)carve((size_t)N * RMAX * 2);
    bf16*  x0p     = (bf16*)          carve((size_t)N * 256 * 2);   // residual + GEMM in
    bf16*  x1p     = (bf16*)          carve((size_t)E * 256 * 2);
    bf16*  x1u_b   = (bf16*)          carve((size_t)E * 256 * 2);   // bf16 copy of x_1_u
    bf16*  R1      = (bf16*)          carve((size_t)N * 512 * 2);   // 8 MB overlay
    bf16*  R2      = (bf16*)          carve((size_t)E * 256 * 3 * 2); // 3 MB overlay

    // overlay views
    bf16* kv1   = R1;                          // stage 1 [N,512]
    bf16* q2    = R1;                          // stage 2 [N,256]  (kv1 dead)
    bf16* attn2 = R1 + (size_t)N * 256;        // stage 2 [N,256]
    bf16* mha2  = R1;                          // stage 2 [N,256]  (q2 dead)
    bf16* q1    = R2;                          // stage 1 [E,256]
    bf16* attn1 = R2 + (size_t)E * 256;        // stage 1 [E,256]
    bf16* mha1  = R2 + (size_t)E * 512;        // stage 1 [E,256]
    bf16* kv2   = R2;                          // stage 2 [E,512]  (q1,attn1 dead)

    // wcat element offsets
    const int O_NW = 0, O_EW = 65536, O_AIW = 131072, O_AOW = 327680,
              O_BIW = 393216, O_BOW = 589824, O_NB = 655360, O_EB = 655616,
              O_AIB = 655872, O_AOB = 656640, O_BIB = 656896, O_BOB = 657664;

    ConvDesc cd;
    const int srcix[12] = {3, 5, 7, 9, 11, 13, 4, 6, 8, 10, 12, 14};
    const int offs [12] = {O_NW, O_EW, O_AIW, O_AOW, O_BIW, O_BOW,
                           O_NB, O_EB, O_AIB, O_AOB, O_BIB, O_BOB};
    const int cnts [12] = {65536, 65536, 196608, 65536, 196608, 65536,
                           256, 256, 768, 256, 768, 256};
    for (int i = 0; i < 12; i++) {
        cd.src[i] = (const float*)d_in[srcix[i]];
        cd.dstoff[i] = offs[i];
        cd.cnt[i] = cnts[i];
    }
    conv_weights<<<12 * 64, 256, 0, stream>>>(cd, wcat);

    hipMemsetAsync(col_cnt, 0, (size_t)E * 4, stream);
    build_lists<<<N, 256, 0, stream>>>((const float*)d_in[2], col_cnt, col_idx,
                                       row_cnt, row_idx);

    // projections (fp32 inputs -> bf16 out; x0p/x1p double as residuals)
    gemm_bt<true><<<(N/128)*2, 256, 0, stream>>>(d_in[0], wcat + O_NW,
                                                 wcat + O_NB, x0p, 256, 256, 2);
    gemm_bt<true><<<(E/128)*2, 256, 0, stream>>>(d_in[1], wcat + O_EW,
                                                 wcat + O_EB, x1p, 256, 256, 2);

    // ---- stage 1: node -> edge (edges query nodes; neighbors = H columns) ----
    gemm_bt<false><<<(E/128)*2, 256, 0, stream>>>(x1p, wcat + O_AIW,
                                                  wcat + O_AIB, q1, 256, 256, 2);
    gemm_bt<false><<<(N/128)*4, 256, 0, stream>>>(x0p, wcat + O_AIW + 65536,
                                                  wcat + O_AIB + 256, kv1, 256, 512, 4);
    sparse_attn<<<E, 256, 0, stream>>>(q1, kv1, kv1 + 256, 512,
                                       col_cnt, col_idx, CMAX, N - 1, attn1);
    gemm_bt<false><<<(E/128)*2, 256, 0, stream>>>(attn1, wcat + O_AOW,
                                                  wcat + O_AOB, mha1, 256, 256, 2);
    residual_ln<<<E, 256, 0, stream>>>(x1p, mha1, (const float*)d_in[15],
                                       (const float*)d_in[16], out1, x1u_b);

    // ---- stage 2: edge -> node (nodes query updated edges; neighbors = H rows) ----
    gemm_bt<false><<<(N/128)*2, 256, 0, stream>>>(x0p, wcat + O_BIW,
                                                  wcat + O_BIB, q2, 256, 256, 2);
    gemm_bt<false><<<(E/128)*4, 256, 0, stream>>>(x1u_b, wcat + O_BIW + 65536,
                                                  wcat + O_BIB + 256, kv2, 256, 512, 4);
    sparse_attn<<<N, 256, 0, stream>>>(q2, kv2, kv2 + 256, 512,
                                       row_cnt, row_idx, RMAX, E - 1, attn2);
    gemm_bt<false><<<(N/128)*2, 256, 0, stream>>>(attn2, wcat + O_BOW,
                                                  wcat + O_BOB, mha2, 256, 256, 2);
    residual_ln<<<N, 256, 0, stream>>>(x0p, mha2, (const float*)d_in[17],
                                       (const float*)d_in[18], out0, nullptr);
}

// Round 9
// 273.683 us; speedup vs baseline: 4.5696x; 1.0528x over previous
//
#include <hip/hip_runtime.h>
#include <hip/hip_bf16.h>

using bf16 = __hip_bfloat16;
typedef __attribute__((ext_vector_type(4))) float  f32x4;
typedef __attribute__((ext_vector_type(8))) short  s16x8;

#define QSTRIDE 1040   // 128*8 + 16 pad (bf16 elems per k-quad block)
#define ASTRIDE 520    // 64*8 + 8 pad   (gemm_ln A tile)
#define BSTRIDE 2064   // 256*8 + 16 pad (gemm_ln B tile)
#define CMAX 256
#define RMAX 128

// ---------------------------------------------------------------------------
// fp32 -> bf16 conversion of all weights/biases into one arena (14 segments,
// pre-concatenated for the fused GEMMs).
// ---------------------------------------------------------------------------
struct ConvDesc { const float* src[14]; int dstoff[14]; int cnt[14]; };

__global__ __launch_bounds__(256)
void conv_weights(ConvDesc d, bf16* __restrict__ dst)
{
    const int seg = blockIdx.x >> 6;
    const int blk = blockIdx.x & 63;
    const float* __restrict__ s = d.src[seg];
    bf16* __restrict__ o = dst + d.dstoff[seg];
    const int n = d.cnt[seg];
    for (int i = blk * 256 + threadIdx.x; i < n; i += 64 * 256)
        o[i] = __float2bfloat16(s[i]);
}

// ---------------------------------------------------------------------------
// Sparse neighbor lists from incidence H [8192, 2048] fp32 (exactly 0.0/1.0).
// ---------------------------------------------------------------------------
__global__ __launch_bounds__(256)
void build_lists(const float* __restrict__ H, int* __restrict__ col_cnt,
                 unsigned short* __restrict__ col_idx, int* __restrict__ row_cnt,
                 unsigned short* __restrict__ row_idx)
{
    const int n = blockIdx.x, t = threadIdx.x;
    __shared__ int rc;
    if (t == 0) rc = 0;
    __syncthreads();

    const float* Hp = H + (size_t)n * 2048 + t * 8;
    f32x4 h0 = *(const f32x4*)Hp;
    f32x4 h1 = *(const f32x4*)(Hp + 4);
    float hv[8];
#pragma unroll
    for (int j = 0; j < 4; j++) { hv[j] = h0[j]; hv[4 + j] = h1[j]; }

#pragma unroll
    for (int j = 0; j < 8; j++) {
        if (hv[j] != 0.f) {
            const int e = t * 8 + j;
            const int sr = atomicAdd(&rc, 1);
            if (sr < RMAX) row_idx[(size_t)n * RMAX + sr] = (unsigned short)e;
            const int sc = atomicAdd(&col_cnt[e], 1);
            if (sc < CMAX) col_idx[(size_t)e * CMAX + sc] = (unsigned short)n;
        }
    }
    __syncthreads();
    if (t == 0) row_cnt[n] = (rc < RMAX) ? rc : RMAX;
}

// ---------------------------------------------------------------------------
// MFMA GEMM: C[M,N] = A[M,K]*W[N,K]^T + bias[N], bf16 in/out. 128x128 tile.
// ---------------------------------------------------------------------------
__global__ __launch_bounds__(256, 2)
void gemm_bt(const bf16* __restrict__ A, const bf16* __restrict__ W,
             const bf16* __restrict__ bias, bf16* __restrict__ outB,
             int K, int N, int tilesN)
{
    __shared__ __align__(16) bf16 As[4 * QSTRIDE];
    __shared__ __align__(16) bf16 Bs[4 * QSTRIDE];

    const int t    = threadIdx.x;
    const int lane = t & 63;
    const int w    = t >> 6;
    const int wm   = (w >> 1) * 64;
    const int wn   = (w & 1) * 64;
    const int tm   = (blockIdx.x / tilesN) * 128;
    const int tn   = (blockIdx.x % tilesN) * 128;

    f32x4 acc[4][4];
#pragma unroll
    for (int i = 0; i < 4; i++)
#pragma unroll
        for (int j = 0; j < 4; j++)
#pragma unroll
            for (int r = 0; r < 4; r++) acc[i][j][r] = 0.f;

    const int m0 = t >> 2,         q0 = t & 3;
    const int m1 = (t + 256) >> 2, q1 = (t + 256) & 3;
    const int fq = lane >> 4, fr = lane & 15;

    for (int k0 = 0; k0 < K; k0 += 32) {
        s16x8 sa0 = *(const s16x8*)(A + (size_t)(tm + m0) * K + k0 + q0 * 8);
        s16x8 sa1 = *(const s16x8*)(A + (size_t)(tm + m1) * K + k0 + q1 * 8);
        s16x8 sb0 = *(const s16x8*)(W + (size_t)(tn + m0) * K + k0 + q0 * 8);
        s16x8 sb1 = *(const s16x8*)(W + (size_t)(tn + m1) * K + k0 + q1 * 8);

        __syncthreads();
        *(s16x8*)&As[q0 * QSTRIDE + m0 * 8] = sa0;
        *(s16x8*)&As[q1 * QSTRIDE + m1 * 8] = sa1;
        *(s16x8*)&Bs[q0 * QSTRIDE + m0 * 8] = sb0;
        *(s16x8*)&Bs[q1 * QSTRIDE + m1 * 8] = sb1;
        __syncthreads();

        s16x8 af[4], bfv[4];
#pragma unroll
        for (int i = 0; i < 4; i++) {
            af[i]  = *(const s16x8*)&As[fq * QSTRIDE + (wm + i * 16 + fr) * 8];
            bfv[i] = *(const s16x8*)&Bs[fq * QSTRIDE + (wn + i * 16 + fr) * 8];
        }
#pragma unroll
        for (int i = 0; i < 4; i++)
#pragma unroll
            for (int j = 0; j < 4; j++)
                acc[i][j] = __builtin_amdgcn_mfma_f32_16x16x32_bf16(
                    af[i], bfv[j], acc[i][j], 0, 0, 0);
    }

#pragma unroll
    for (int j = 0; j < 4; j++) {
        const int ncol = tn + wn + j * 16 + fr;
        const float bj = __bfloat162float(bias[ncol]);
#pragma unroll
        for (int i = 0; i < 4; i++)
#pragma unroll
            for (int r = 0; r < 4; r++) {
                const int mrow = tm + wm + i * 16 + fq * 4 + r;
                outB[(size_t)mrow * N + ncol] = __float2bfloat16(acc[i][j][r] + bj);
            }
    }
}

// ---------------------------------------------------------------------------
// Fused node+edge projection: rows 0..8191 = x_0 @ node_w^T + node_b,
// rows 8192..10239 = x_1 @ edge_w^T + edge_b. A fp32 converted in staging.
// W: [node_w | edge_w] concat; bias: [node_b | edge_b]. K=N=256.
// Grid: 80 row-tiles x 2 col-tiles = 160 blocks. (R8 bug: launched 320.)
// ---------------------------------------------------------------------------
__global__ __launch_bounds__(256, 2)
void gemm_proj(const float* __restrict__ X0, const float* __restrict__ X1,
               const bf16* __restrict__ Wc, const bf16* __restrict__ biasc,
               bf16* __restrict__ outB)
{
    __shared__ __align__(16) bf16 As[4 * QSTRIDE];
    __shared__ __align__(16) bf16 Bs[4 * QSTRIDE];

    const int t    = threadIdx.x;
    const int lane = t & 63;
    const int w    = t >> 6;
    const int wm   = (w >> 1) * 64;
    const int wn   = (w & 1) * 64;
    const int bt   = blockIdx.x >> 1;
    const int tn   = (blockIdx.x & 1) * 128;
    if (bt >= 80) return;   // defensive: grid must be 160

    const float* __restrict__ A = (bt < 64) ? X0 : X1;
    const int arow = (bt < 64) ? bt * 128 : (bt - 64) * 128;
    const bf16* __restrict__ W    = Wc    + ((bt < 64) ? 0 : 65536);
    const bf16* __restrict__ bias = biasc + ((bt < 64) ? 0 : 256);
    const int tm = bt * 128;   // output row base

    f32x4 acc[4][4];
#pragma unroll
    for (int i = 0; i < 4; i++)
#pragma unroll
        for (int j = 0; j < 4; j++)
#pragma unroll
            for (int r = 0; r < 4; r++) acc[i][j][r] = 0.f;

    const int m0 = t >> 2,         q0 = t & 3;
    const int m1 = (t + 256) >> 2, q1 = (t + 256) & 3;
    const int fq = lane >> 4, fr = lane & 15;

    for (int k0 = 0; k0 < 256; k0 += 32) {
        f32x4 a0l = *(const f32x4*)(A + (size_t)(arow + m0) * 256 + k0 + q0 * 8);
        f32x4 a0h = *(const f32x4*)(A + (size_t)(arow + m0) * 256 + k0 + q0 * 8 + 4);
        f32x4 a1l = *(const f32x4*)(A + (size_t)(arow + m1) * 256 + k0 + q1 * 8);
        f32x4 a1h = *(const f32x4*)(A + (size_t)(arow + m1) * 256 + k0 + q1 * 8 + 4);
        union { s16x8 v; bf16 e[8]; } u0, u1;
#pragma unroll
        for (int j = 0; j < 4; j++) {
            u0.e[j] = __float2bfloat16(a0l[j]); u0.e[4 + j] = __float2bfloat16(a0h[j]);
            u1.e[j] = __float2bfloat16(a1l[j]); u1.e[4 + j] = __float2bfloat16(a1h[j]);
        }
        s16x8 sb0 = *(const s16x8*)(W + (size_t)(tn + m0) * 256 + k0 + q0 * 8);
        s16x8 sb1 = *(const s16x8*)(W + (size_t)(tn + m1) * 256 + k0 + q1 * 8);

        __syncthreads();
        *(s16x8*)&As[q0 * QSTRIDE + m0 * 8] = u0.v;
        *(s16x8*)&As[q1 * QSTRIDE + m1 * 8] = u1.v;
        *(s16x8*)&Bs[q0 * QSTRIDE + m0 * 8] = sb0;
        *(s16x8*)&Bs[q1 * QSTRIDE + m1 * 8] = sb1;
        __syncthreads();

        s16x8 af[4], bfv[4];
#pragma unroll
        for (int i = 0; i < 4; i++) {
            af[i]  = *(const s16x8*)&As[fq * QSTRIDE + (wm + i * 16 + fr) * 8];
            bfv[i] = *(const s16x8*)&Bs[fq * QSTRIDE + (wn + i * 16 + fr) * 8];
        }
#pragma unroll
        for (int i = 0; i < 4; i++)
#pragma unroll
            for (int j = 0; j < 4; j++)
                acc[i][j] = __builtin_amdgcn_mfma_f32_16x16x32_bf16(
                    af[i], bfv[j], acc[i][j], 0, 0, 0);
    }

#pragma unroll
    for (int j = 0; j < 4; j++) {
        const int ncol = tn + wn + j * 16 + fr;
        const float bj = __bfloat162float(bias[ncol]);
#pragma unroll
        for (int i = 0; i < 4; i++)
#pragma unroll
            for (int r = 0; r < 4; r++) {
                const int mrow = tm + wm + i * 16 + fq * 4 + r;
                outB[(size_t)mrow * 256 + ncol] = __float2bfloat16(acc[i][j][r] + bj);
            }
    }
}

// ---------------------------------------------------------------------------
// Fused out-proj + residual + LayerNorm. Block = 64 rows x 256 cols (full LN
// rows). y = LN(xp + A@W^T + bias) * g + b -> fp32 d_out (+ optional bf16).
// ---------------------------------------------------------------------------
__global__ __launch_bounds__(256, 2)
void gemm_ln(const bf16* __restrict__ A, const bf16* __restrict__ W,
             const float* __restrict__ biasF, const bf16* __restrict__ xp,
             const float* __restrict__ g, const float* __restrict__ b,
             float* __restrict__ outF, bf16* __restrict__ outB)
{
    __shared__ __align__(16) bf16 As[4 * ASTRIDE];
    __shared__ __align__(16) bf16 Bs[4 * BSTRIDE];
    __shared__ float rs1[64], rs2[64];

    const int t    = threadIdx.x;
    const int lane = t & 63;
    const int w    = t >> 6;
    const int fq   = lane >> 4;
    const int fr   = lane & 15;
    const int tm   = blockIdx.x * 64;

    if (t < 64) { rs1[t] = 0.f; rs2[t] = 0.f; }

    f32x4 acc[4][4];
#pragma unroll
    for (int i = 0; i < 4; i++)
#pragma unroll
        for (int j = 0; j < 4; j++)
#pragma unroll
            for (int r = 0; r < 4; r++) acc[i][j][r] = 0.f;

    const int mA = t >> 2, qA = t & 3;

    for (int k0 = 0; k0 < 256; k0 += 32) {
        s16x8 sa = *(const s16x8*)(A + (size_t)(tm + mA) * 256 + k0 + qA * 8);
        s16x8 sb[4];
#pragma unroll
        for (int s = 0; s < 4; s++)
            sb[s] = *(const s16x8*)(W + (size_t)(mA + 64 * s) * 256 + k0 + qA * 8);

        __syncthreads();
        *(s16x8*)&As[qA * ASTRIDE + mA * 8] = sa;
#pragma unroll
        for (int s = 0; s < 4; s++)
            *(s16x8*)&Bs[qA * BSTRIDE + (mA + 64 * s) * 8] = sb[s];
        __syncthreads();

        s16x8 af[4], bfv[4];
#pragma unroll
        for (int i = 0; i < 4; i++) {
            af[i]  = *(const s16x8*)&As[fq * ASTRIDE + (i * 16 + fr) * 8];
            bfv[i] = *(const s16x8*)&Bs[fq * BSTRIDE + (w * 64 + i * 16 + fr) * 8];
        }
#pragma unroll
        for (int i = 0; i < 4; i++)
#pragma unroll
            for (int j = 0; j < 4; j++)
                acc[i][j] = __builtin_amdgcn_mfma_f32_16x16x32_bf16(
                    af[i], bfv[j], acc[i][j], 0, 0, 0);
    }

    float bj[4], gj[4], bbj[4];
    int colv[4];
#pragma unroll
    for (int j = 0; j < 4; j++) {
        colv[j] = w * 64 + j * 16 + fr;
        bj[j]  = biasF[colv[j]];
        gj[j]  = g[colv[j]];
        bbj[j] = b[colv[j]];
    }

#pragma unroll
    for (int i = 0; i < 4; i++) {
#pragma unroll
        for (int r = 0; r < 4; r++) {
            const int row = i * 16 + fq * 4 + r;
            float t1 = 0.f, t2 = 0.f;
#pragma unroll
            for (int j = 0; j < 4; j++) {
                float v = acc[i][j][r] + bj[j]
                        + __bfloat162float(xp[(size_t)(tm + row) * 256 + colv[j]]);
                acc[i][j][r] = v;
                t1 += v;
                t2 += v * v;
            }
#pragma unroll
            for (int o = 1; o < 16; o <<= 1) {
                t1 += __shfl_xor(t1, o);
                t2 += __shfl_xor(t2, o);
            }
            if (fr == 0) {
                atomicAdd(&rs1[row], t1);
                atomicAdd(&rs2[row], t2);
            }
        }
    }
    __syncthreads();

#pragma unroll
    for (int i = 0; i < 4; i++) {
#pragma unroll
        for (int r = 0; r < 4; r++) {
            const int row = i * 16 + fq * 4 + r;
            const float mu  = rs1[row] * (1.f / 256.f);
            const float var = rs2[row] * (1.f / 256.f) - mu * mu;
            const float rstd = rsqrtf(var + 1e-5f);
#pragma unroll
            for (int j = 0; j < 4; j++) {
                const float y = (acc[i][j][r] - mu) * rstd * gj[j] + bbj[j];
                outF[(size_t)(tm + row) * 256 + colv[j]] = y;
                if (outB) outB[(size_t)(tm + row) * 256 + colv[j]] = __float2bfloat16(y);
            }
        }
    }
}

// ---------------------------------------------------------------------------
// Sparse masked attention, vectorized gather. Block = query row, wave = head.
// 8 groups x 8 lanes: group = neighbor, lane = 8-dim slice (16 B loads).
// ---------------------------------------------------------------------------
__global__ __launch_bounds__(256)
void sparse_attn(const bf16* __restrict__ Q, int qs,
                 const bf16* __restrict__ Kb, const bf16* __restrict__ Vb, int kvs,
                 const int* __restrict__ cnts, const unsigned short* __restrict__ idx,
                 int lmax, int idxmask, bf16* __restrict__ out)
{
    __shared__ float sc[4][CMAX];
    __shared__ unsigned short nls[CMAX];
    const int qi   = blockIdx.x;
    const int h    = threadIdx.x >> 6;
    const int lane = threadIdx.x & 63;
    const int grp  = lane >> 3;
    const int sub  = lane & 7;

    int n = cnts[qi];
    if (n > lmax) n = lmax;

    if (h == 0)
        for (int i = lane; i < n; i += 64)
            nls[i] = (unsigned short)(((int)idx[(size_t)qi * lmax + i]) & idxmask);
    __syncthreads();

    if (n <= 0) {
        out[(size_t)qi * 256 + h * 64 + lane] = __float2bfloat16(0.f);
        return;
    }

    float qv[8];
    {
        union { f32x4 v; unsigned short u[8]; } qu;
        qu.v = *(const f32x4*)(Q + (size_t)qi * qs + h * 64 + sub * 8);
#pragma unroll
        for (int j = 0; j < 8; j++)
            qv[j] = __uint_as_float(((unsigned)qu.u[j]) << 16) * 0.125f;
    }

    float mx = -1e30f;
#pragma unroll 2
    for (int base = 0; base < n; base += 8) {
        const int i = base + grp;
        float s = -1e30f;
        if (i < n) {
            const int nb = nls[i];
            union { f32x4 v; unsigned short u[8]; } ku;
            ku.v = *(const f32x4*)(Kb + (size_t)nb * kvs + h * 64 + sub * 8);
            float a = 0.f;
#pragma unroll
            for (int j = 0; j < 8; j++)
                a += __uint_as_float(((unsigned)ku.u[j]) << 16) * qv[j];
            a += __shfl_xor(a, 1);
            a += __shfl_xor(a, 2);
            a += __shfl_xor(a, 4);
            if (sub == 0) sc[h][i] = a;
            s = a;
        }
        mx = fmaxf(mx, s);
    }
#pragma unroll
    for (int o = 32; o > 0; o >>= 1) mx = fmaxf(mx, __shfl_xor(mx, o));

    float sum = 0.f;
    for (int base = 0; base < n; base += 64) {
        const int i = base + lane;
        if (i < n) {
            const float p = __expf(sc[h][i] - mx);
            sc[h][i] = p;
            sum += p;
        }
    }
#pragma unroll
    for (int o = 32; o > 0; o >>= 1) sum += __shfl_xor(sum, o);
    const float inv = 1.f / sum;

    float oa[8];
#pragma unroll
    for (int j = 0; j < 8; j++) oa[j] = 0.f;
#pragma unroll 2
    for (int base = 0; base < n; base += 8) {
        const int i = base + grp;
        if (i < n) {
            const float p = sc[h][i];
            const int nb = nls[i];
            union { f32x4 v; unsigned short u[8]; } vu;
            vu.v = *(const f32x4*)(Vb + (size_t)nb * kvs + h * 64 + sub * 8);
#pragma unroll
            for (int j = 0; j < 8; j++)
                oa[j] += p * __uint_as_float(((unsigned)vu.u[j]) << 16);
        }
    }
#pragma unroll
    for (int j = 0; j < 8; j++) {
        oa[j] += __shfl_xor(oa[j], 8);
        oa[j] += __shfl_xor(oa[j], 16);
        oa[j] += __shfl_xor(oa[j], 32);
    }
    if (grp == 0) {
        union { s16x8 v; bf16 e[8]; } ou;
#pragma unroll
        for (int j = 0; j < 8; j++) ou.e[j] = __float2bfloat16(oa[j] * inv);
        *(s16x8*)(out + (size_t)qi * 256 + h * 64 + sub * 8) = ou.v;
    }
}

// ---------------------------------------------------------------------------
extern "C" void kernel_launch(void* const* d_in, const int* in_sizes, int n_in,
                              void* d_out, int out_size, void* d_ws, size_t ws_size,
                              hipStream_t stream)
{
    const int N = 8192, E = 2048;

    float* out0 = (float*)d_out;                   // x_0_u [N,256] fp32
    float* out1 = (float*)d_out + (size_t)N * 256; // x_1_u [E,256] fp32

    char* wp = (char*)d_ws;
    auto carve = [&](size_t bytes) { void* p = wp; wp += (bytes + 15) & ~size_t(15); return p; };

    bf16*  wcat    = (bf16*)          carve(657408 * 2);
    int*   col_cnt = (int*)           carve((size_t)E * 4);
    int*   row_cnt = (int*)           carve((size_t)N * 4);
    unsigned short* col_idx = (unsigned short*)carve((size_t)E * CMAX * 2);
    unsigned short* row_idx = (unsigned short*)carve((size_t)N * RMAX * 2);
    bf16*  xp01    = (bf16*) carve((size_t)(N + E) * 256 * 2);  // x0p | x1p
    bf16*  kvq     = (bf16*) carve((size_t)N * 768 * 2);        // k1|v1|q2
    bf16*  q1      = (bf16*) carve((size_t)E * 256 * 2);
    bf16*  attn1   = (bf16*) carve((size_t)E * 256 * 2);
    bf16*  x1u_b   = (bf16*) carve((size_t)E * 256 * 2);
    bf16*  kv2     = (bf16*) carve((size_t)E * 512 * 2);
    bf16*  attn2   = (bf16*) carve((size_t)N * 256 * 2);

    bf16* x0p = xp01;
    bf16* x1p = xp01 + (size_t)N * 256;

    // wcat element offsets (all 8-elem aligned)
    const int O_PW   = 0;        // node_w | edge_w           (131072)
    const int O_PB   = 131072;   // node_b | edge_b           (512)
    const int O_KVQ  = 131584;   // n2e Wk,Wv | e2n Wq        (196608)
    const int O_KVQB = 328192;   // n2e bk,bv | e2n bq        (768)
    const int O_Q1W  = 328960;   // n2e Wq                    (65536)
    const int O_Q1B  = 394496;   // n2e bq                    (256)
    const int O_KV2W = 394752;   // e2n Wk,Wv                 (131072)
    const int O_KV2B = 525824;   // e2n bk,bv                 (512)
    const int O_O1W  = 526336;   // n2e_out_w                 (65536)
    const int O_O2W  = 591872;   // e2n_out_w                 (65536)

    ConvDesc cd;
    const float* srcs[14] = {
        (const float*)d_in[3], (const float*)d_in[5],
        (const float*)d_in[4], (const float*)d_in[6],
        (const float*)d_in[7] + 65536, (const float*)d_in[11],
        (const float*)d_in[8] + 256,   (const float*)d_in[12],
        (const float*)d_in[7],         (const float*)d_in[8],
        (const float*)d_in[11] + 65536,(const float*)d_in[12] + 256,
        (const float*)d_in[9],         (const float*)d_in[13]
    };
    const int offs[14] = {O_PW, O_PW + 65536, O_PB, O_PB + 256,
                          O_KVQ, O_KVQ + 131072, O_KVQB, O_KVQB + 512,
                          O_Q1W, O_Q1B, O_KV2W, O_KV2B, O_O1W, O_O2W};
    const int cnts[14] = {65536, 65536, 256, 256, 131072, 65536, 512, 256,
                          65536, 256, 131072, 512, 65536, 65536};
    for (int i = 0; i < 14; i++) { cd.src[i] = srcs[i]; cd.dstoff[i] = offs[i]; cd.cnt[i] = cnts[i]; }
    conv_weights<<<14 * 64, 256, 0, stream>>>(cd, wcat);

    hipMemsetAsync(col_cnt, 0, (size_t)E * 4, stream);
    build_lists<<<N, 256, 0, stream>>>((const float*)d_in[2], col_cnt, col_idx,
                                       row_cnt, row_idx);

    // fused projections: 80 row-tiles x 2 col-tiles = 160 blocks
    gemm_proj<<<160, 256, 0, stream>>>((const float*)d_in[0], (const float*)d_in[1],
                                       wcat + O_PW, wcat + O_PB, xp01);

    // fused kv1 + q2 from x0p: [N, 768] = [k1(256) | v1(256) | q2(256)]
    gemm_bt<<<(N / 128) * 6, 256, 0, stream>>>(x0p, wcat + O_KVQ, wcat + O_KVQB,
                                               kvq, 256, 768, 6);
    // q1 from x1p
    gemm_bt<<<(E / 128) * 2, 256, 0, stream>>>(x1p, wcat + O_Q1W, wcat + O_Q1B,
                                               q1, 256, 256, 2);

    // ---- stage 1: node -> edge ----
    sparse_attn<<<E, 256, 0, stream>>>(q1, 256, kvq, kvq + 256, 768,
                                       col_cnt, col_idx, CMAX, N - 1, attn1);
    gemm_ln<<<E / 64, 256, 0, stream>>>(attn1, wcat + O_O1W, (const float*)d_in[10],
                                        x1p, (const float*)d_in[15], (const float*)d_in[16],
                                        out1, x1u_b);

    // ---- stage 2: edge -> node ----
    gemm_bt<<<(E / 128) * 4, 256, 0, stream>>>(x1u_b, wcat + O_KV2W, wcat + O_KV2B,
                                               kv2, 256, 512, 4);
    sparse_attn<<<N, 256, 0, stream>>>(kvq + 512, 768, kv2, kv2 + 256, 512,
                                       row_cnt, row_idx, RMAX, E - 1, attn2);
    gemm_ln<<<N / 64, 256, 0, stream>>>(attn2, wcat + O_O2W, (const float*)d_in[14],
                                        x0p, (const float*)d_in[17], (const float*)d_in[18],
                                        out0, nullptr);
}

// Round 10
// 273.178 us; speedup vs baseline: 4.5781x; 1.0018x over previous
//
#include <hip/hip_runtime.h>
#include <hip/hip_bf16.h>

using bf16 = __hip_bfloat16;
typedef __attribute__((ext_vector_type(4))) float  f32x4;
typedef __attribute__((ext_vector_type(8))) short  s16x8;

#define QSTRIDE 1040   // 128*8 + 16 pad (bf16 elems per k-quad block)
#define ASTRIDE 520    // 64*8 + 8 pad   (gemm_ln A tile)
#define BSTRIDE 2064   // 256*8 + 16 pad (gemm_ln B tile)
#define CMAX 256
#define RMAX 128

// ---------------------------------------------------------------------------
// fp32 -> bf16 weight conversion (14 segments) + col_cnt zero-fill (seg 14).
// ---------------------------------------------------------------------------
struct ConvDesc { const float* src[14]; int dstoff[14]; int cnt[14]; };

__global__ __launch_bounds__(256)
void conv_weights(ConvDesc d, bf16* __restrict__ dst, int* __restrict__ cz, int czn)
{
    const int seg = blockIdx.x >> 6;
    const int blk = blockIdx.x & 63;
    if (seg == 14) {                       // zero col_cnt
        for (int i = blk * 256 + threadIdx.x; i < czn; i += 64 * 256)
            cz[i] = 0;
        return;
    }
    const float* __restrict__ s = d.src[seg];
    bf16* __restrict__ o = dst + d.dstoff[seg];
    const int n = d.cnt[seg];
    for (int i = blk * 256 + threadIdx.x; i < n; i += 64 * 256)
        o[i] = __float2bfloat16(s[i]);
}

// ---------------------------------------------------------------------------
// Fused: blocks 0..8191 = build_lists row; blocks 8192..8351 = gemm_proj.
// Shared memory aliased (max of the two, not sum).
// build: sparse lists from H [8192,2048] fp32 (exactly 0/1).
// proj:  rows 0..8191 = x_0@node_w^T+node_b; rows 8192..10239 = x_1@edge_w^T+edge_b.
// ---------------------------------------------------------------------------
__global__ __launch_bounds__(256, 2)
void build_proj(const float* __restrict__ H, int* __restrict__ col_cnt,
                unsigned short* __restrict__ col_idx, int* __restrict__ row_cnt,
                unsigned short* __restrict__ row_idx,
                const float* __restrict__ X0, const float* __restrict__ X1,
                const bf16* __restrict__ Wc, const bf16* __restrict__ biasc,
                bf16* __restrict__ outB)
{
    __shared__ __align__(16) char smem[8 * QSTRIDE * 2];   // 16.6 KB
    const int t = threadIdx.x;

    if (blockIdx.x < 8192) {
        // ---------------- build_lists ----------------
        int* rc = (int*)smem;
        const int n = blockIdx.x;
        if (t == 0) *rc = 0;
        __syncthreads();

        const float* Hp = H + (size_t)n * 2048 + t * 8;
        f32x4 h0 = *(const f32x4*)Hp;
        f32x4 h1 = *(const f32x4*)(Hp + 4);
        float hv[8];
#pragma unroll
        for (int j = 0; j < 4; j++) { hv[j] = h0[j]; hv[4 + j] = h1[j]; }

#pragma unroll
        for (int j = 0; j < 8; j++) {
            if (hv[j] != 0.f) {
                const int e = t * 8 + j;
                const int sr = atomicAdd(rc, 1);
                if (sr < RMAX) row_idx[(size_t)n * RMAX + sr] = (unsigned short)e;
                const int sc = atomicAdd(&col_cnt[e], 1);
                if (sc < CMAX) col_idx[(size_t)e * CMAX + sc] = (unsigned short)n;
            }
        }
        __syncthreads();
        if (t == 0) row_cnt[n] = (*rc < RMAX) ? *rc : RMAX;
        return;
    }

    // ---------------- gemm_proj ----------------
    bf16* As = (bf16*)smem;
    bf16* Bs = As + 4 * QSTRIDE;

    const int lane = t & 63;
    const int w    = t >> 6;
    const int wm   = (w >> 1) * 64;
    const int wn   = (w & 1) * 64;
    const int pb   = blockIdx.x - 8192;       // 0..159
    const int bt   = pb >> 1;                 // 0..79 row tile
    const int tn   = (pb & 1) * 128;

    const float* __restrict__ A = (bt < 64) ? X0 : X1;
    const int arow = (bt < 64) ? bt * 128 : (bt - 64) * 128;
    const bf16* __restrict__ W    = Wc    + ((bt < 64) ? 0 : 65536);
    const bf16* __restrict__ bias = biasc + ((bt < 64) ? 0 : 256);
    const int tm = bt * 128;

    f32x4 acc[4][4];
#pragma unroll
    for (int i = 0; i < 4; i++)
#pragma unroll
        for (int j = 0; j < 4; j++)
#pragma unroll
            for (int r = 0; r < 4; r++) acc[i][j][r] = 0.f;

    const int m0 = t >> 2,         q0 = t & 3;
    const int m1 = (t + 256) >> 2, q1 = (t + 256) & 3;
    const int fq = lane >> 4, fr = lane & 15;

    for (int k0 = 0; k0 < 256; k0 += 32) {
        f32x4 a0l = *(const f32x4*)(A + (size_t)(arow + m0) * 256 + k0 + q0 * 8);
        f32x4 a0h = *(const f32x4*)(A + (size_t)(arow + m0) * 256 + k0 + q0 * 8 + 4);
        f32x4 a1l = *(const f32x4*)(A + (size_t)(arow + m1) * 256 + k0 + q1 * 8);
        f32x4 a1h = *(const f32x4*)(A + (size_t)(arow + m1) * 256 + k0 + q1 * 8 + 4);
        union { s16x8 v; bf16 e[8]; } u0, u1;
#pragma unroll
        for (int j = 0; j < 4; j++) {
            u0.e[j] = __float2bfloat16(a0l[j]); u0.e[4 + j] = __float2bfloat16(a0h[j]);
            u1.e[j] = __float2bfloat16(a1l[j]); u1.e[4 + j] = __float2bfloat16(a1h[j]);
        }
        s16x8 sb0 = *(const s16x8*)(W + (size_t)(tn + m0) * 256 + k0 + q0 * 8);
        s16x8 sb1 = *(const s16x8*)(W + (size_t)(tn + m1) * 256 + k0 + q1 * 8);

        __syncthreads();
        *(s16x8*)&As[q0 * QSTRIDE + m0 * 8] = u0.v;
        *(s16x8*)&As[q1 * QSTRIDE + m1 * 8] = u1.v;
        *(s16x8*)&Bs[q0 * QSTRIDE + m0 * 8] = sb0;
        *(s16x8*)&Bs[q1 * QSTRIDE + m1 * 8] = sb1;
        __syncthreads();

        s16x8 af[4], bfv[4];
#pragma unroll
        for (int i = 0; i < 4; i++) {
            af[i]  = *(const s16x8*)&As[fq * QSTRIDE + (wm + i * 16 + fr) * 8];
            bfv[i] = *(const s16x8*)&Bs[fq * QSTRIDE + (wn + i * 16 + fr) * 8];
        }
#pragma unroll
        for (int i = 0; i < 4; i++)
#pragma unroll
            for (int j = 0; j < 4; j++)
                acc[i][j] = __builtin_amdgcn_mfma_f32_16x16x32_bf16(
                    af[i], bfv[j], acc[i][j], 0, 0, 0);
    }

#pragma unroll
    for (int j = 0; j < 4; j++) {
        const int ncol = tn + wn + j * 16 + fr;
        const float bj = __bfloat162float(bias[ncol]);
#pragma unroll
        for (int i = 0; i < 4; i++)
#pragma unroll
            for (int r = 0; r < 4; r++) {
                const int mrow = tm + wm + i * 16 + fq * 4 + r;
                outB[(size_t)mrow * 256 + ncol] = __float2bfloat16(acc[i][j][r] + bj);
            }
    }
}

// ---------------------------------------------------------------------------
// Dual MFMA GEMM (two independent problems, block-range split), bf16 in/out.
// Blocks < nblk0: C0[M0,N0] = A0@W0^T+b0; else C1 = A1@W1^T+b1. K=256.
// ---------------------------------------------------------------------------
__global__ __launch_bounds__(256, 2)
void gemm_dual(const bf16* __restrict__ A0, const bf16* __restrict__ W0,
               const bf16* __restrict__ bias0, bf16* __restrict__ out0,
               int N0, int tiles0, int nblk0,
               const bf16* __restrict__ A1, const bf16* __restrict__ W1,
               const bf16* __restrict__ bias1, bf16* __restrict__ out1,
               int N1, int tiles1)
{
    __shared__ __align__(16) bf16 As[4 * QSTRIDE];
    __shared__ __align__(16) bf16 Bs[4 * QSTRIDE];

    const int t    = threadIdx.x;
    const int lane = t & 63;
    const int w    = t >> 6;
    const int wm   = (w >> 1) * 64;
    const int wn   = (w & 1) * 64;

    const bool second = (blockIdx.x >= (unsigned)nblk0);
    const int  bi     = second ? (blockIdx.x - nblk0) : blockIdx.x;
    const bf16* __restrict__ A    = second ? A1 : A0;
    const bf16* __restrict__ W    = second ? W1 : W0;
    const bf16* __restrict__ bias = second ? bias1 : bias0;
    bf16* __restrict__ outB       = second ? out1 : out0;
    const int N      = second ? N1 : N0;
    const int tilesN = second ? tiles1 : tiles0;
    const int tm = (bi / tilesN) * 128;
    const int tn = (bi % tilesN) * 128;

    f32x4 acc[4][4];
#pragma unroll
    for (int i = 0; i < 4; i++)
#pragma unroll
        for (int j = 0; j < 4; j++)
#pragma unroll
            for (int r = 0; r < 4; r++) acc[i][j][r] = 0.f;

    const int m0 = t >> 2,         q0 = t & 3;
    const int m1 = (t + 256) >> 2, q1 = (t + 256) & 3;
    const int fq = lane >> 4, fr = lane & 15;

    for (int k0 = 0; k0 < 256; k0 += 32) {
        s16x8 sa0 = *(const s16x8*)(A + (size_t)(tm + m0) * 256 + k0 + q0 * 8);
        s16x8 sa1 = *(const s16x8*)(A + (size_t)(tm + m1) * 256 + k0 + q1 * 8);
        s16x8 sb0 = *(const s16x8*)(W + (size_t)(tn + m0) * 256 + k0 + q0 * 8);
        s16x8 sb1 = *(const s16x8*)(W + (size_t)(tn + m1) * 256 + k0 + q1 * 8);

        __syncthreads();
        *(s16x8*)&As[q0 * QSTRIDE + m0 * 8] = sa0;
        *(s16x8*)&As[q1 * QSTRIDE + m1 * 8] = sa1;
        *(s16x8*)&Bs[q0 * QSTRIDE + m0 * 8] = sb0;
        *(s16x8*)&Bs[q1 * QSTRIDE + m1 * 8] = sb1;
        __syncthreads();

        s16x8 af[4], bfv[4];
#pragma unroll
        for (int i = 0; i < 4; i++) {
            af[i]  = *(const s16x8*)&As[fq * QSTRIDE + (wm + i * 16 + fr) * 8];
            bfv[i] = *(const s16x8*)&Bs[fq * QSTRIDE + (wn + i * 16 + fr) * 8];
        }
#pragma unroll
        for (int i = 0; i < 4; i++)
#pragma unroll
            for (int j = 0; j < 4; j++)
                acc[i][j] = __builtin_amdgcn_mfma_f32_16x16x32_bf16(
                    af[i], bfv[j], acc[i][j], 0, 0, 0);
    }

#pragma unroll
    for (int j = 0; j < 4; j++) {
        const int ncol = tn + wn + j * 16 + fr;
        const float bj = __bfloat162float(bias[ncol]);
#pragma unroll
        for (int i = 0; i < 4; i++)
#pragma unroll
            for (int r = 0; r < 4; r++) {
                const int mrow = tm + wm + i * 16 + fq * 4 + r;
                outB[(size_t)mrow * N + ncol] = __float2bfloat16(acc[i][j][r] + bj);
            }
    }
}

// ---------------------------------------------------------------------------
// Fused out-proj + residual + LayerNorm. Block = 64 rows x 256 cols.
// y = LN(xp + A@W^T + bias) * g + b -> fp32 d_out (+ optional bf16 copy).
// ---------------------------------------------------------------------------
__global__ __launch_bounds__(256, 2)
void gemm_ln(const bf16* __restrict__ A, const bf16* __restrict__ W,
             const float* __restrict__ biasF, const bf16* __restrict__ xp,
             const float* __restrict__ g, const float* __restrict__ b,
             float* __restrict__ outF, bf16* __restrict__ outB)
{
    __shared__ __align__(16) bf16 As[4 * ASTRIDE];
    __shared__ __align__(16) bf16 Bs[4 * BSTRIDE];
    __shared__ float rs1[64], rs2[64];

    const int t    = threadIdx.x;
    const int lane = t & 63;
    const int w    = t >> 6;
    const int fq   = lane >> 4;
    const int fr   = lane & 15;
    const int tm   = blockIdx.x * 64;

    if (t < 64) { rs1[t] = 0.f; rs2[t] = 0.f; }

    f32x4 acc[4][4];
#pragma unroll
    for (int i = 0; i < 4; i++)
#pragma unroll
        for (int j = 0; j < 4; j++)
#pragma unroll
            for (int r = 0; r < 4; r++) acc[i][j][r] = 0.f;

    const int mA = t >> 2, qA = t & 3;

    for (int k0 = 0; k0 < 256; k0 += 32) {
        s16x8 sa = *(const s16x8*)(A + (size_t)(tm + mA) * 256 + k0 + qA * 8);
        s16x8 sb[4];
#pragma unroll
        for (int s = 0; s < 4; s++)
            sb[s] = *(const s16x8*)(W + (size_t)(mA + 64 * s) * 256 + k0 + qA * 8);

        __syncthreads();
        *(s16x8*)&As[qA * ASTRIDE + mA * 8] = sa;
#pragma unroll
        for (int s = 0; s < 4; s++)
            *(s16x8*)&Bs[qA * BSTRIDE + (mA + 64 * s) * 8] = sb[s];
        __syncthreads();

        s16x8 af[4], bfv[4];
#pragma unroll
        for (int i = 0; i < 4; i++) {
            af[i]  = *(const s16x8*)&As[fq * ASTRIDE + (i * 16 + fr) * 8];
            bfv[i] = *(const s16x8*)&Bs[fq * BSTRIDE + (w * 64 + i * 16 + fr) * 8];
        }
#pragma unroll
        for (int i = 0; i < 4; i++)
#pragma unroll
            for (int j = 0; j < 4; j++)
                acc[i][j] = __builtin_amdgcn_mfma_f32_16x16x32_bf16(
                    af[i], bfv[j], acc[i][j], 0, 0, 0);
    }

    float bj[4], gj[4], bbj[4];
    int colv[4];
#pragma unroll
    for (int j = 0; j < 4; j++) {
        colv[j] = w * 64 + j * 16 + fr;
        bj[j]  = biasF[colv[j]];
        gj[j]  = g[colv[j]];
        bbj[j] = b[colv[j]];
    }

#pragma unroll
    for (int i = 0; i < 4; i++) {
#pragma unroll
        for (int r = 0; r < 4; r++) {
            const int row = i * 16 + fq * 4 + r;
            float t1 = 0.f, t2 = 0.f;
#pragma unroll
            for (int j = 0; j < 4; j++) {
                float v = acc[i][j][r] + bj[j]
                        + __bfloat162float(xp[(size_t)(tm + row) * 256 + colv[j]]);
                acc[i][j][r] = v;
                t1 += v;
                t2 += v * v;
            }
#pragma unroll
            for (int o = 1; o < 16; o <<= 1) {
                t1 += __shfl_xor(t1, o);
                t2 += __shfl_xor(t2, o);
            }
            if (fr == 0) {
                atomicAdd(&rs1[row], t1);
                atomicAdd(&rs2[row], t2);
            }
        }
    }
    __syncthreads();

#pragma unroll
    for (int i = 0; i < 4; i++) {
#pragma unroll
        for (int r = 0; r < 4; r++) {
            const int row = i * 16 + fq * 4 + r;
            const float mu  = rs1[row] * (1.f / 256.f);
            const float var = rs2[row] * (1.f / 256.f) - mu * mu;
            const float rstd = rsqrtf(var + 1e-5f);
#pragma unroll
            for (int j = 0; j < 4; j++) {
                const float y = (acc[i][j][r] - mu) * rstd * gj[j] + bbj[j];
                outF[(size_t)(tm + row) * 256 + colv[j]] = y;
                if (outB) outB[(size_t)(tm + row) * 256 + colv[j]] = __float2bfloat16(y);
            }
        }
    }
}

// ---------------------------------------------------------------------------
// Sparse masked attention, vectorized gather. Block = query row, wave = head.
// 8 groups x 8 lanes: group = neighbor, lane = 8-dim slice (16 B loads).
// ---------------------------------------------------------------------------
__global__ __launch_bounds__(256)
void sparse_attn(const bf16* __restrict__ Q, int qs,
                 const bf16* __restrict__ Kb, const bf16* __restrict__ Vb, int kvs,
                 const int* __restrict__ cnts, const unsigned short* __restrict__ idx,
                 int lmax, int idxmask, bf16* __restrict__ out)
{
    __shared__ float sc[4][CMAX];
    __shared__ unsigned short nls[CMAX];
    const int qi   = blockIdx.x;
    const int h    = threadIdx.x >> 6;
    const int lane = threadIdx.x & 63;
    const int grp  = lane >> 3;
    const int sub  = lane & 7;

    int n = cnts[qi];
    if (n > lmax) n = lmax;

    if (h == 0)
        for (int i = lane; i < n; i += 64)
            nls[i] = (unsigned short)(((int)idx[(size_t)qi * lmax + i]) & idxmask);
    __syncthreads();

    if (n <= 0) {
        out[(size_t)qi * 256 + h * 64 + lane] = __float2bfloat16(0.f);
        return;
    }

    float qv[8];
    {
        union { f32x4 v; unsigned short u[8]; } qu;
        qu.v = *(const f32x4*)(Q + (size_t)qi * qs + h * 64 + sub * 8);
#pragma unroll
        for (int j = 0; j < 8; j++)
            qv[j] = __uint_as_float(((unsigned)qu.u[j]) << 16) * 0.125f;
    }

    float mx = -1e30f;
#pragma unroll 2
    for (int base = 0; base < n; base += 8) {
        const int i = base + grp;
        float s = -1e30f;
        if (i < n) {
            const int nb = nls[i];
            union { f32x4 v; unsigned short u[8]; } ku;
            ku.v = *(const f32x4*)(Kb + (size_t)nb * kvs + h * 64 + sub * 8);
            float a = 0.f;
#pragma unroll
            for (int j = 0; j < 8; j++)
                a += __uint_as_float(((unsigned)ku.u[j]) << 16) * qv[j];
            a += __shfl_xor(a, 1);
            a += __shfl_xor(a, 2);
            a += __shfl_xor(a, 4);
            if (sub == 0) sc[h][i] = a;
            s = a;
        }
        mx = fmaxf(mx, s);
    }
#pragma unroll
    for (int o = 32; o > 0; o >>= 1) mx = fmaxf(mx, __shfl_xor(mx, o));

    float sum = 0.f;
    for (int base = 0; base < n; base += 64) {
        const int i = base + lane;
        if (i < n) {
            const float p = __expf(sc[h][i] - mx);
            sc[h][i] = p;
            sum += p;
        }
    }
#pragma unroll
    for (int o = 32; o > 0; o >>= 1) sum += __shfl_xor(sum, o);
    const float inv = 1.f / sum;

    float oa[8];
#pragma unroll
    for (int j = 0; j < 8; j++) oa[j] = 0.f;
#pragma unroll 2
    for (int base = 0; base < n; base += 8) {
        const int i = base + grp;
        if (i < n) {
            const float p = sc[h][i];
            const int nb = nls[i];
            union { f32x4 v; unsigned short u[8]; } vu;
            vu.v = *(const f32x4*)(Vb + (size_t)nb * kvs + h * 64 + sub * 8);
#pragma unroll
            for (int j = 0; j < 8; j++)
                oa[j] += p * __uint_as_float(((unsigned)vu.u[j]) << 16);
        }
    }
#pragma unroll
    for (int j = 0; j < 8; j++) {
        oa[j] += __shfl_xor(oa[j], 8);
        oa[j] += __shfl_xor(oa[j], 16);
        oa[j] += __shfl_xor(oa[j], 32);
    }
    if (grp == 0) {
        union { s16x8 v; bf16 e[8]; } ou;
#pragma unroll
        for (int j = 0; j < 8; j++) ou.e[j] = __float2bfloat16(oa[j] * inv);
        *(s16x8*)(out + (size_t)qi * 256 + h * 64 + sub * 8) = ou.v;
    }
}

// ---------------------------------------------------------------------------
extern "C" void kernel_launch(void* const* d_in, const int* in_sizes, int n_in,
                              void* d_out, int out_size, void* d_ws, size_t ws_size,
                              hipStream_t stream)
{
    const int N = 8192, E = 2048;

    float* out0 = (float*)d_out;                   // x_0_u [N,256] fp32
    float* out1 = (float*)d_out + (size_t)N * 256; // x_1_u [E,256] fp32

    char* wp = (char*)d_ws;
    auto carve = [&](size_t bytes) { void* p = wp; wp += (bytes + 15) & ~size_t(15); return p; };

    bf16*  wcat    = (bf16*)          carve(657408 * 2);
    int*   col_cnt = (int*)           carve((size_t)E * 4);
    int*   row_cnt = (int*)           carve((size_t)N * 4);
    unsigned short* col_idx = (unsigned short*)carve((size_t)E * CMAX * 2);
    unsigned short* row_idx = (unsigned short*)carve((size_t)N * RMAX * 2);
    bf16*  xp01    = (bf16*) carve((size_t)(N + E) * 256 * 2);  // x0p | x1p
    bf16*  kvq     = (bf16*) carve((size_t)N * 768 * 2);        // k1|v1|q2
    bf16*  q1      = (bf16*) carve((size_t)E * 256 * 2);
    bf16*  attn1   = (bf16*) carve((size_t)E * 256 * 2);
    bf16*  x1u_b   = (bf16*) carve((size_t)E * 256 * 2);
    bf16*  kv2     = (bf16*) carve((size_t)E * 512 * 2);
    bf16*  attn2   = (bf16*) carve((size_t)N * 256 * 2);

    bf16* x0p = xp01;
    bf16* x1p = xp01 + (size_t)N * 256;

    // wcat element offsets (all 8-elem aligned)
    const int O_PW   = 0;        // node_w | edge_w           (131072)
    const int O_PB   = 131072;   // node_b | edge_b           (512)
    const int O_KVQ  = 131584;   // n2e Wk,Wv | e2n Wq        (196608)
    const int O_KVQB = 328192;   // n2e bk,bv | e2n bq        (768)
    const int O_Q1W  = 328960;   // n2e Wq                    (65536)
    const int O_Q1B  = 394496;   // n2e bq                    (256)
    const int O_KV2W = 394752;   // e2n Wk,Wv                 (131072)
    const int O_KV2B = 525824;   // e2n bk,bv                 (512)
    const int O_O1W  = 526336;   // n2e_out_w                 (65536)
    const int O_O2W  = 591872;   // e2n_out_w                 (65536)

    ConvDesc cd;
    const float* srcs[14] = {
        (const float*)d_in[3], (const float*)d_in[5],
        (const float*)d_in[4], (const float*)d_in[6],
        (const float*)d_in[7] + 65536, (const float*)d_in[11],
        (const float*)d_in[8] + 256,   (const float*)d_in[12],
        (const float*)d_in[7],         (const float*)d_in[8],
        (const float*)d_in[11] + 65536,(const float*)d_in[12] + 256,
        (const float*)d_in[9],         (const float*)d_in[13]
    };
    const int offs[14] = {O_PW, O_PW + 65536, O_PB, O_PB + 256,
                          O_KVQ, O_KVQ + 131072, O_KVQB, O_KVQB + 512,
                          O_Q1W, O_Q1B, O_KV2W, O_KV2B, O_O1W, O_O2W};
    const int cnts[14] = {65536, 65536, 256, 256, 131072, 65536, 512, 256,
                          65536, 256, 131072, 512, 65536, 65536};
    for (int i = 0; i < 14; i++) { cd.src[i] = srcs[i]; cd.dstoff[i] = offs[i]; cd.cnt[i] = cnts[i]; }

    // 1. weights -> bf16 arena + zero col_cnt (seg 14)
    conv_weights<<<15 * 64, 256, 0, stream>>>(cd, wcat, col_cnt, E);

    // 2. fused: sparse lists from H (blocks 0..8191) + projections (8192..8351)
    build_proj<<<8192 + 160, 256, 0, stream>>>((const float*)d_in[2], col_cnt,
                                               col_idx, row_cnt, row_idx,
                                               (const float*)d_in[0], (const float*)d_in[1],
                                               wcat + O_PW, wcat + O_PB, xp01);

    // 3. fused kvq (384 blocks) + q1 (32 blocks)
    gemm_dual<<<384 + 32, 256, 0, stream>>>(x0p, wcat + O_KVQ, wcat + O_KVQB, kvq,
                                            768, 6, 384,
                                            x1p, wcat + O_Q1W, wcat + O_Q1B, q1,
                                            256, 2);

    // ---- stage 1: node -> edge ----
    sparse_attn<<<E, 256, 0, stream>>>(q1, 256, kvq, kvq + 256, 768,
                                       col_cnt, col_idx, CMAX, N - 1, attn1);
    gemm_ln<<<E / 64, 256, 0, stream>>>(attn1, wcat + O_O1W, (const float*)d_in[10],
                                        x1p, (const float*)d_in[15], (const float*)d_in[16],
                                        out1, x1u_b);

    // ---- stage 2: edge -> node ----
    gemm_dual<<<64, 256, 0, stream>>>(x1u_b, wcat + O_KV2W, wcat + O_KV2B, kv2,
                                      512, 4, 64,
                                      nullptr, nullptr, nullptr, nullptr, 256, 2);
    sparse_attn<<<N, 256, 0, stream>>>(kvq + 512, 768, kv2, kv2 + 256, 512,
                                       row_cnt, row_idx, RMAX, E - 1, attn2);
    gemm_ln<<<N / 64, 256, 0, stream>>>(attn2, wcat + O_O2W, (const float*)d_in[14],
                                        x0p, (const float*)d_in[17], (const float*)d_in[18],
                                        out0, nullptr);
}

// Round 11
// 268.610 us; speedup vs baseline: 4.6559x; 1.0170x over previous
//
#include <hip/hip_runtime.h>
#include <hip/hip_bf16.h>

using bf16 = __hip_bfloat16;
typedef __attribute__((ext_vector_type(4))) float  f32x4;
typedef __attribute__((ext_vector_type(8))) short  s16x8;

#define QSTRIDE 1040   // 128*8 + 16 pad (bf16 elems per k-quad block)
#define ASTRIDE 520    // 64*8 + 8 pad   (gemm_ln A tile)
#define BSTRIDE 2064   // 256*8 + 16 pad (gemm_ln B tile)
#define CMAX 256
#define RMAX 128

// ---------------------------------------------------------------------------
// fp32 -> bf16 weight conversion (14 segments) + col_cnt zero-fill (seg 14).
// ---------------------------------------------------------------------------
struct ConvDesc { const float* src[14]; int dstoff[14]; int cnt[14]; };

__global__ __launch_bounds__(256)
void conv_weights(ConvDesc d, bf16* __restrict__ dst, int* __restrict__ cz, int czn)
{
    const int seg = blockIdx.x >> 6;
    const int blk = blockIdx.x & 63;
    if (seg == 14) {                       // zero col_cnt
        for (int i = blk * 256 + threadIdx.x; i < czn; i += 64 * 256)
            cz[i] = 0;
        return;
    }
    const float* __restrict__ s = d.src[seg];
    bf16* __restrict__ o = dst + d.dstoff[seg];
    const int n = d.cnt[seg];
    for (int i = blk * 256 + threadIdx.x; i < n; i += 64 * 256)
        o[i] = __float2bfloat16(s[i]);
}

// ---------------------------------------------------------------------------
// Sparse neighbor lists from H [8192,2048] fp32 (exactly 0/1).
// 1024 blocks x 8 rows, 2-deep register prefetch: row n+1024's load is in
// flight while row n's nonzero-scan + atomics run. Tiny LDS -> high occupancy.
// ---------------------------------------------------------------------------
__global__ __launch_bounds__(256)
void build_lists(const float* __restrict__ H, int* __restrict__ col_cnt,
                 unsigned short* __restrict__ col_idx, int* __restrict__ row_cnt,
                 unsigned short* __restrict__ row_idx)
{
    __shared__ int rc;
    const int t = threadIdx.x;

    int n = blockIdx.x;
    const float* Hp = H + (size_t)n * 2048 + t * 8;
    f32x4 c0 = *(const f32x4*)Hp;
    f32x4 c1 = *(const f32x4*)(Hp + 4);

    while (n < 8192) {
        const int nn = n + 1024;
        f32x4 p0, p1;
        if (nn < 8192) {                       // prefetch next row
            const float* Hq = H + (size_t)nn * 2048 + t * 8;
            p0 = *(const f32x4*)Hq;
            p1 = *(const f32x4*)(Hq + 4);
        }

        if (t == 0) rc = 0;
        __syncthreads();

        float hv[8];
#pragma unroll
        for (int j = 0; j < 4; j++) { hv[j] = c0[j]; hv[4 + j] = c1[j]; }

#pragma unroll
        for (int j = 0; j < 8; j++) {
            if (hv[j] != 0.f) {
                const int e = t * 8 + j;
                const int sr = atomicAdd(&rc, 1);
                if (sr < RMAX) row_idx[(size_t)n * RMAX + sr] = (unsigned short)e;
                const int sc = atomicAdd(&col_cnt[e], 1);
                if (sc < CMAX) col_idx[(size_t)e * CMAX + sc] = (unsigned short)n;
            }
        }
        __syncthreads();
        if (t == 0) row_cnt[n] = (rc < RMAX) ? rc : RMAX;

        n = nn; c0 = p0; c1 = p1;
    }
}

// ---------------------------------------------------------------------------
// Fused node+edge projection: rows 0..8191 = x_0@node_w^T+node_b,
// rows 8192..10239 = x_1@edge_w^T+edge_b. A fp32 converted in staging.
// Grid: 80 row-tiles x 2 col-tiles = 160 blocks.
// ---------------------------------------------------------------------------
__global__ __launch_bounds__(256, 2)
void gemm_proj(const float* __restrict__ X0, const float* __restrict__ X1,
               const bf16* __restrict__ Wc, const bf16* __restrict__ biasc,
               bf16* __restrict__ outB)
{
    __shared__ __align__(16) bf16 As[4 * QSTRIDE];
    __shared__ __align__(16) bf16 Bs[4 * QSTRIDE];

    const int t    = threadIdx.x;
    const int lane = t & 63;
    const int w    = t >> 6;
    const int wm   = (w >> 1) * 64;
    const int wn   = (w & 1) * 64;
    const int bt   = blockIdx.x >> 1;
    const int tn   = (blockIdx.x & 1) * 128;
    if (bt >= 80) return;

    const float* __restrict__ A = (bt < 64) ? X0 : X1;
    const int arow = (bt < 64) ? bt * 128 : (bt - 64) * 128;
    const bf16* __restrict__ W    = Wc    + ((bt < 64) ? 0 : 65536);
    const bf16* __restrict__ bias = biasc + ((bt < 64) ? 0 : 256);
    const int tm = bt * 128;

    f32x4 acc[4][4];
#pragma unroll
    for (int i = 0; i < 4; i++)
#pragma unroll
        for (int j = 0; j < 4; j++)
#pragma unroll
            for (int r = 0; r < 4; r++) acc[i][j][r] = 0.f;

    const int m0 = t >> 2,         q0 = t & 3;
    const int m1 = (t + 256) >> 2, q1 = (t + 256) & 3;
    const int fq = lane >> 4, fr = lane & 15;

    for (int k0 = 0; k0 < 256; k0 += 32) {
        f32x4 a0l = *(const f32x4*)(A + (size_t)(arow + m0) * 256 + k0 + q0 * 8);
        f32x4 a0h = *(const f32x4*)(A + (size_t)(arow + m0) * 256 + k0 + q0 * 8 + 4);
        f32x4 a1l = *(const f32x4*)(A + (size_t)(arow + m1) * 256 + k0 + q1 * 8);
        f32x4 a1h = *(const f32x4*)(A + (size_t)(arow + m1) * 256 + k0 + q1 * 8 + 4);
        union { s16x8 v; bf16 e[8]; } u0, u1;
#pragma unroll
        for (int j = 0; j < 4; j++) {
            u0.e[j] = __float2bfloat16(a0l[j]); u0.e[4 + j] = __float2bfloat16(a0h[j]);
            u1.e[j] = __float2bfloat16(a1l[j]); u1.e[4 + j] = __float2bfloat16(a1h[j]);
        }
        s16x8 sb0 = *(const s16x8*)(W + (size_t)(tn + m0) * 256 + k0 + q0 * 8);
        s16x8 sb1 = *(const s16x8*)(W + (size_t)(tn + m1) * 256 + k0 + q1 * 8);

        __syncthreads();
        *(s16x8*)&As[q0 * QSTRIDE + m0 * 8] = u0.v;
        *(s16x8*)&As[q1 * QSTRIDE + m1 * 8] = u1.v;
        *(s16x8*)&Bs[q0 * QSTRIDE + m0 * 8] = sb0;
        *(s16x8*)&Bs[q1 * QSTRIDE + m1 * 8] = sb1;
        __syncthreads();

        s16x8 af[4], bfv[4];
#pragma unroll
        for (int i = 0; i < 4; i++) {
            af[i]  = *(const s16x8*)&As[fq * QSTRIDE + (wm + i * 16 + fr) * 8];
            bfv[i] = *(const s16x8*)&Bs[fq * QSTRIDE + (wn + i * 16 + fr) * 8];
        }
#pragma unroll
        for (int i = 0; i < 4; i++)
#pragma unroll
            for (int j = 0; j < 4; j++)
                acc[i][j] = __builtin_amdgcn_mfma_f32_16x16x32_bf16(
                    af[i], bfv[j], acc[i][j], 0, 0, 0);
    }

#pragma unroll
    for (int j = 0; j < 4; j++) {
        const int ncol = tn + wn + j * 16 + fr;
        const float bj = __bfloat162float(bias[ncol]);
#pragma unroll
        for (int i = 0; i < 4; i++)
#pragma unroll
            for (int r = 0; r < 4; r++) {
                const int mrow = tm + wm + i * 16 + fq * 4 + r;
                outB[(size_t)mrow * 256 + ncol] = __float2bfloat16(acc[i][j][r] + bj);
            }
    }
}

// ---------------------------------------------------------------------------
// Dual MFMA GEMM (two independent problems, block-range split), bf16 in/out.
// ---------------------------------------------------------------------------
__global__ __launch_bounds__(256, 2)
void gemm_dual(const bf16* __restrict__ A0, const bf16* __restrict__ W0,
               const bf16* __restrict__ bias0, bf16* __restrict__ out0,
               int N0, int tiles0, int nblk0,
               const bf16* __restrict__ A1, const bf16* __restrict__ W1,
               const bf16* __restrict__ bias1, bf16* __restrict__ out1,
               int N1, int tiles1)
{
    __shared__ __align__(16) bf16 As[4 * QSTRIDE];
    __shared__ __align__(16) bf16 Bs[4 * QSTRIDE];

    const int t    = threadIdx.x;
    const int lane = t & 63;
    const int w    = t >> 6;
    const int wm   = (w >> 1) * 64;
    const int wn   = (w & 1) * 64;

    const bool second = (blockIdx.x >= (unsigned)nblk0);
    const int  bi     = second ? (blockIdx.x - nblk0) : blockIdx.x;
    const bf16* __restrict__ A    = second ? A1 : A0;
    const bf16* __restrict__ W    = second ? W1 : W0;
    const bf16* __restrict__ bias = second ? bias1 : bias0;
    bf16* __restrict__ outB       = second ? out1 : out0;
    const int N      = second ? N1 : N0;
    const int tilesN = second ? tiles1 : tiles0;
    const int tm = (bi / tilesN) * 128;
    const int tn = (bi % tilesN) * 128;

    f32x4 acc[4][4];
#pragma unroll
    for (int i = 0; i < 4; i++)
#pragma unroll
        for (int j = 0; j < 4; j++)
#pragma unroll
            for (int r = 0; r < 4; r++) acc[i][j][r] = 0.f;

    const int m0 = t >> 2,         q0 = t & 3;
    const int m1 = (t + 256) >> 2, q1 = (t + 256) & 3;
    const int fq = lane >> 4, fr = lane & 15;

    for (int k0 = 0; k0 < 256; k0 += 32) {
        s16x8 sa0 = *(const s16x8*)(A + (size_t)(tm + m0) * 256 + k0 + q0 * 8);
        s16x8 sa1 = *(const s16x8*)(A + (size_t)(tm + m1) * 256 + k0 + q1 * 8);
        s16x8 sb0 = *(const s16x8*)(W + (size_t)(tn + m0) * 256 + k0 + q0 * 8);
        s16x8 sb1 = *(const s16x8*)(W + (size_t)(tn + m1) * 256 + k0 + q1 * 8);

        __syncthreads();
        *(s16x8*)&As[q0 * QSTRIDE + m0 * 8] = sa0;
        *(s16x8*)&As[q1 * QSTRIDE + m1 * 8] = sa1;
        *(s16x8*)&Bs[q0 * QSTRIDE + m0 * 8] = sb0;
        *(s16x8*)&Bs[q1 * QSTRIDE + m1 * 8] = sb1;
        __syncthreads();

        s16x8 af[4], bfv[4];
#pragma unroll
        for (int i = 0; i < 4; i++) {
            af[i]  = *(const s16x8*)&As[fq * QSTRIDE + (wm + i * 16 + fr) * 8];
            bfv[i] = *(const s16x8*)&Bs[fq * QSTRIDE + (wn + i * 16 + fr) * 8];
        }
#pragma unroll
        for (int i = 0; i < 4; i++)
#pragma unroll
            for (int j = 0; j < 4; j++)
                acc[i][j] = __builtin_amdgcn_mfma_f32_16x16x32_bf16(
                    af[i], bfv[j], acc[i][j], 0, 0, 0);
    }

#pragma unroll
    for (int j = 0; j < 4; j++) {
        const int ncol = tn + wn + j * 16 + fr;
        const float bj = __bfloat162float(bias[ncol]);
#pragma unroll
        for (int i = 0; i < 4; i++)
#pragma unroll
            for (int r = 0; r < 4; r++) {
                const int mrow = tm + wm + i * 16 + fq * 4 + r;
                outB[(size_t)mrow * N + ncol] = __float2bfloat16(acc[i][j][r] + bj);
            }
    }
}

// ---------------------------------------------------------------------------
// Fused out-proj + residual + LayerNorm. Block = 64 rows x 256 cols.
// y = LN(xp + A@W^T + bias) * g + b -> fp32 d_out (+ optional bf16 copy).
// ---------------------------------------------------------------------------
__global__ __launch_bounds__(256, 2)
void gemm_ln(const bf16* __restrict__ A, const bf16* __restrict__ W,
             const float* __restrict__ biasF, const bf16* __restrict__ xp,
             const float* __restrict__ g, const float* __restrict__ b,
             float* __restrict__ outF, bf16* __restrict__ outB)
{
    __shared__ __align__(16) bf16 As[4 * ASTRIDE];
    __shared__ __align__(16) bf16 Bs[4 * BSTRIDE];
    __shared__ float rs1[64], rs2[64];

    const int t    = threadIdx.x;
    const int lane = t & 63;
    const int w    = t >> 6;
    const int fq   = lane >> 4;
    const int fr   = lane & 15;
    const int tm   = blockIdx.x * 64;

    if (t < 64) { rs1[t] = 0.f; rs2[t] = 0.f; }

    f32x4 acc[4][4];
#pragma unroll
    for (int i = 0; i < 4; i++)
#pragma unroll
        for (int j = 0; j < 4; j++)
#pragma unroll
            for (int r = 0; r < 4; r++) acc[i][j][r] = 0.f;

    const int mA = t >> 2, qA = t & 3;

    for (int k0 = 0; k0 < 256; k0 += 32) {
        s16x8 sa = *(const s16x8*)(A + (size_t)(tm + mA) * 256 + k0 + qA * 8);
        s16x8 sb[4];
#pragma unroll
        for (int s = 0; s < 4; s++)
            sb[s] = *(const s16x8*)(W + (size_t)(mA + 64 * s) * 256 + k0 + qA * 8);

        __syncthreads();
        *(s16x8*)&As[qA * ASTRIDE + mA * 8] = sa;
#pragma unroll
        for (int s = 0; s < 4; s++)
            *(s16x8*)&Bs[qA * BSTRIDE + (mA + 64 * s) * 8] = sb[s];
        __syncthreads();

        s16x8 af[4], bfv[4];
#pragma unroll
        for (int i = 0; i < 4; i++) {
            af[i]  = *(const s16x8*)&As[fq * ASTRIDE + (i * 16 + fr) * 8];
            bfv[i] = *(const s16x8*)&Bs[fq * BSTRIDE + (w * 64 + i * 16 + fr) * 8];
        }
#pragma unroll
        for (int i = 0; i < 4; i++)
#pragma unroll
            for (int j = 0; j < 4; j++)
                acc[i][j] = __builtin_amdgcn_mfma_f32_16x16x32_bf16(
                    af[i], bfv[j], acc[i][j], 0, 0, 0);
    }

    float bj[4], gj[4], bbj[4];
    int colv[4];
#pragma unroll
    for (int j = 0; j < 4; j++) {
        colv[j] = w * 64 + j * 16 + fr;
        bj[j]  = biasF[colv[j]];
        gj[j]  = g[colv[j]];
        bbj[j] = b[colv[j]];
    }

#pragma unroll
    for (int i = 0; i < 4; i++) {
#pragma unroll
        for (int r = 0; r < 4; r++) {
            const int row = i * 16 + fq * 4 + r;
            float t1 = 0.f, t2 = 0.f;
#pragma unroll
            for (int j = 0; j < 4; j++) {
                float v = acc[i][j][r] + bj[j]
                        + __bfloat162float(xp[(size_t)(tm + row) * 256 + colv[j]]);
                acc[i][j][r] = v;
                t1 += v;
                t2 += v * v;
            }
#pragma unroll
            for (int o = 1; o < 16; o <<= 1) {
                t1 += __shfl_xor(t1, o);
                t2 += __shfl_xor(t2, o);
            }
            if (fr == 0) {
                atomicAdd(&rs1[row], t1);
                atomicAdd(&rs2[row], t2);
            }
        }
    }
    __syncthreads();

#pragma unroll
    for (int i = 0; i < 4; i++) {
#pragma unroll
        for (int r = 0; r < 4; r++) {
            const int row = i * 16 + fq * 4 + r;
            const float mu  = rs1[row] * (1.f / 256.f);
            const float var = rs2[row] * (1.f / 256.f) - mu * mu;
            const float rstd = rsqrtf(var + 1e-5f);
#pragma unroll
            for (int j = 0; j < 4; j++) {
                const float y = (acc[i][j][r] - mu) * rstd * gj[j] + bbj[j];
                outF[(size_t)(tm + row) * 256 + colv[j]] = y;
                if (outB) outB[(size_t)(tm + row) * 256 + colv[j]] = __float2bfloat16(y);
            }
        }
    }
}

// ---------------------------------------------------------------------------
// Sparse masked attention, vectorized gather. Block = query row, wave = head.
// 8 groups x 8 lanes: group = neighbor, lane = 8-dim slice (16 B loads).
// ---------------------------------------------------------------------------
__global__ __launch_bounds__(256)
void sparse_attn(const bf16* __restrict__ Q, int qs,
                 const bf16* __restrict__ Kb, const bf16* __restrict__ Vb, int kvs,
                 const int* __restrict__ cnts, const unsigned short* __restrict__ idx,
                 int lmax, int idxmask, bf16* __restrict__ out)
{
    __shared__ float sc[4][CMAX];
    __shared__ unsigned short nls[CMAX];
    const int qi   = blockIdx.x;
    const int h    = threadIdx.x >> 6;
    const int lane = threadIdx.x & 63;
    const int grp  = lane >> 3;
    const int sub  = lane & 7;

    int n = cnts[qi];
    if (n > lmax) n = lmax;

    if (h == 0)
        for (int i = lane; i < n; i += 64)
            nls[i] = (unsigned short)(((int)idx[(size_t)qi * lmax + i]) & idxmask);
    __syncthreads();

    if (n <= 0) {
        out[(size_t)qi * 256 + h * 64 + lane] = __float2bfloat16(0.f);
        return;
    }

    float qv[8];
    {
        union { f32x4 v; unsigned short u[8]; } qu;
        qu.v = *(const f32x4*)(Q + (size_t)qi * qs + h * 64 + sub * 8);
#pragma unroll
        for (int j = 0; j < 8; j++)
            qv[j] = __uint_as_float(((unsigned)qu.u[j]) << 16) * 0.125f;
    }

    float mx = -1e30f;
#pragma unroll 2
    for (int base = 0; base < n; base += 8) {
        const int i = base + grp;
        float s = -1e30f;
        if (i < n) {
            const int nb = nls[i];
            union { f32x4 v; unsigned short u[8]; } ku;
            ku.v = *(const f32x4*)(Kb + (size_t)nb * kvs + h * 64 + sub * 8);
            float a = 0.f;
#pragma unroll
            for (int j = 0; j < 8; j++)
                a += __uint_as_float(((unsigned)ku.u[j]) << 16) * qv[j];
            a += __shfl_xor(a, 1);
            a += __shfl_xor(a, 2);
            a += __shfl_xor(a, 4);
            if (sub == 0) sc[h][i] = a;
            s = a;
        }
        mx = fmaxf(mx, s);
    }
#pragma unroll
    for (int o = 32; o > 0; o >>= 1) mx = fmaxf(mx, __shfl_xor(mx, o));

    float sum = 0.f;
    for (int base = 0; base < n; base += 64) {
        const int i = base + lane;
        if (i < n) {
            const float p = __expf(sc[h][i] - mx);
            sc[h][i] = p;
            sum += p;
        }
    }
#pragma unroll
    for (int o = 32; o > 0; o >>= 1) sum += __shfl_xor(sum, o);
    const float inv = 1.f / sum;

    float oa[8];
#pragma unroll
    for (int j = 0; j < 8; j++) oa[j] = 0.f;
#pragma unroll 2
    for (int base = 0; base < n; base += 8) {
        const int i = base + grp;
        if (i < n) {
            const float p = sc[h][i];
            const int nb = nls[i];
            union { f32x4 v; unsigned short u[8]; } vu;
            vu.v = *(const f32x4*)(Vb + (size_t)nb * kvs + h * 64 + sub * 8);
#pragma unroll
            for (int j = 0; j < 8; j++)
                oa[j] += p * __uint_as_float(((unsigned)vu.u[j]) << 16);
        }
    }
#pragma unroll
    for (int j = 0; j < 8; j++) {
        oa[j] += __shfl_xor(oa[j], 8);
        oa[j] += __shfl_xor(oa[j], 16);
        oa[j] += __shfl_xor(oa[j], 32);
    }
    if (grp == 0) {
        union { s16x8 v; bf16 e[8]; } ou;
#pragma unroll
        for (int j = 0; j < 8; j++) ou.e[j] = __float2bfloat16(oa[j] * inv);
        *(s16x8*)(out + (size_t)qi * 256 + h * 64 + sub * 8) = ou.v;
    }
}

// ---------------------------------------------------------------------------
extern "C" void kernel_launch(void* const* d_in, const int* in_sizes, int n_in,
                              void* d_out, int out_size, void* d_ws, size_t ws_size,
                              hipStream_t stream)
{
    const int N = 8192, E = 2048;

    float* out0 = (float*)d_out;                   // x_0_u [N,256] fp32
    float* out1 = (float*)d_out + (size_t)N * 256; // x_1_u [E,256] fp32

    char* wp = (char*)d_ws;
    auto carve = [&](size_t bytes) { void* p = wp; wp += (bytes + 15) & ~size_t(15); return p; };

    bf16*  wcat    = (bf16*)          carve(657408 * 2);
    int*   col_cnt = (int*)           carve((size_t)E * 4);
    int*   row_cnt = (int*)           carve((size_t)N * 4);
    unsigned short* col_idx = (unsigned short*)carve((size_t)E * CMAX * 2);
    unsigned short* row_idx = (unsigned short*)carve((size_t)N * RMAX * 2);
    bf16*  xp01    = (bf16*) carve((size_t)(N + E) * 256 * 2);  // x0p | x1p
    bf16*  kvq     = (bf16*) carve((size_t)N * 768 * 2);        // k1|v1|q2
    bf16*  q1      = (bf16*) carve((size_t)E * 256 * 2);
    bf16*  attn1   = (bf16*) carve((size_t)E * 256 * 2);
    bf16*  x1u_b   = (bf16*) carve((size_t)E * 256 * 2);
    bf16*  kv2     = (bf16*) carve((size_t)E * 512 * 2);
    bf16*  attn2   = (bf16*) carve((size_t)N * 256 * 2);

    bf16* x0p = xp01;
    bf16* x1p = xp01 + (size_t)N * 256;

    // wcat element offsets (all 8-elem aligned)
    const int O_PW   = 0;        // node_w | edge_w           (131072)
    const int O_PB   = 131072;   // node_b | edge_b           (512)
    const int O_KVQ  = 131584;   // n2e Wk,Wv | e2n Wq        (196608)
    const int O_KVQB = 328192;   // n2e bk,bv | e2n bq        (768)
    const int O_Q1W  = 328960;   // n2e Wq                    (65536)
    const int O_Q1B  = 394496;   // n2e bq                    (256)
    const int O_KV2W = 394752;   // e2n Wk,Wv                 (131072)
    const int O_KV2B = 525824;   // e2n bk,bv                 (512)
    const int O_O1W  = 526336;   // n2e_out_w                 (65536)
    const int O_O2W  = 591872;   // e2n_out_w                 (65536)

    ConvDesc cd;
    const float* srcs[14] = {
        (const float*)d_in[3], (const float*)d_in[5],
        (const float*)d_in[4], (const float*)d_in[6],
        (const float*)d_in[7] + 65536, (const float*)d_in[11],
        (const float*)d_in[8] + 256,   (const float*)d_in[12],
        (const float*)d_in[7],         (const float*)d_in[8],
        (const float*)d_in[11] + 65536,(const float*)d_in[12] + 256,
        (const float*)d_in[9],         (const float*)d_in[13]
    };
    const int offs[14] = {O_PW, O_PW + 65536, O_PB, O_PB + 256,
                          O_KVQ, O_KVQ + 131072, O_KVQB, O_KVQB + 512,
                          O_Q1W, O_Q1B, O_KV2W, O_KV2B, O_O1W, O_O2W};
    const int cnts[14] = {65536, 65536, 256, 256, 131072, 65536, 512, 256,
                          65536, 256, 131072, 512, 65536, 65536};
    for (int i = 0; i < 14; i++) { cd.src[i] = srcs[i]; cd.dstoff[i] = offs[i]; cd.cnt[i] = cnts[i]; }

    // 1. weights -> bf16 arena + zero col_cnt (seg 14)
    conv_weights<<<15 * 64, 256, 0, stream>>>(cd, wcat, col_cnt, E);

    // 2. sparse lists (streaming, pipelined)
    build_lists<<<1024, 256, 0, stream>>>((const float*)d_in[2], col_cnt, col_idx,
                                          row_cnt, row_idx);

    // 3. projections
    gemm_proj<<<160, 256, 0, stream>>>((const float*)d_in[0], (const float*)d_in[1],
                                       wcat + O_PW, wcat + O_PB, xp01);

    // 4. fused kvq (384 blocks) + q1 (32 blocks)
    gemm_dual<<<384 + 32, 256, 0, stream>>>(x0p, wcat + O_KVQ, wcat + O_KVQB, kvq,
                                            768, 6, 384,
                                            x1p, wcat + O_Q1W, wcat + O_Q1B, q1,
                                            256, 2);

    // ---- stage 1: node -> edge ----
    sparse_attn<<<E, 256, 0, stream>>>(q1, 256, kvq, kvq + 256, 768,
                                       col_cnt, col_idx, CMAX, N - 1, attn1);
    gemm_ln<<<E / 64, 256, 0, stream>>>(attn1, wcat + O_O1W, (const float*)d_in[10],
                                        x1p, (const float*)d_in[15], (const float*)d_in[16],
                                        out1, x1u_b);

    // ---- stage 2: edge -> node ----
    gemm_dual<<<64, 256, 0, stream>>>(x1u_b, wcat + O_KV2W, wcat + O_KV2B, kv2,
                                      512, 4, 64,
                                      nullptr, nullptr, nullptr, nullptr, 256, 2);
    sparse_attn<<<N, 256, 0, stream>>>(kvq + 512, 768, kv2, kv2 + 256, 512,
                                       row_cnt, row_idx, RMAX, E - 1, attn2);
    gemm_ln<<<N / 64, 256, 0, stream>>>(attn2, wcat + O_O2W, (const float*)d_in[14],
                                        x0p, (const float*)d_in[17], (const float*)d_in[18],
                                        out0, nullptr);
}